// Round 3
// baseline (727.658 us; speedup 1.0000x reference)
//
#include <hip/hip_runtime.h>

// ---------------------------------------------------------------------------
// InfiniteTransformer on MI355X (gfx950). fp32 I/O (runtime probe keeps bf16
// fallback), bf16 MFMA internals, f32 accum.
// B=4 S=4096 DIM=1024 H=8 DK=DV=64 SEG=512 NSEG=8 EXP=4
// R9: gemm256 inner math switched to v_mfma_f32_32x32x16_bf16 (2x FLOP per
// LDS byte, half the MFMA instructions, minimal fragment reads: 16 A + 8 B
// per K-tile, every fragment read once). Staging / LDS swizzle / 8-phase
// barrier+vmcnt schedule unchanged from the verified R8 structure.
// ln_kernel: one wave per row (wave-only reduce). Full-M MLP as in R8.
// ---------------------------------------------------------------------------

typedef __attribute__((ext_vector_type(8)))  short    short8;   // 8 x bf16 (MFMA A/B frag)
typedef __attribute__((ext_vector_type(4)))  float    f32x4;
typedef __attribute__((ext_vector_type(16))) float    f32x16;   // 32x32 MFMA C/D
typedef __attribute__((ext_vector_type(8)))  unsigned short u16x8;
typedef __attribute__((ext_vector_type(4)))  unsigned short u16x4;

#define B_    4
#define S_    4096
#define H_    8
#define SEG_  512
#define NSEG_ 8
#define QKVN  1536

__device__ __forceinline__ float bf2f(unsigned short u) {
  union { unsigned int i; float f; } x; x.i = ((unsigned int)u) << 16; return x.f;
}
__device__ __forceinline__ unsigned short f2bf(float f) {
  union { float f; unsigned int i; } x; x.f = f;
  unsigned int r = x.i + 0x7FFFu + ((x.i >> 16) & 1u);   // RTNE
  return (unsigned short)(r >> 16);
}
__device__ __forceinline__ float elu1(float x) { return x > 0.f ? x + 1.f : __expf(x); }

__device__ __forceinline__ void async_load16(const unsigned short* g, unsigned short* l) {
  __builtin_amdgcn_global_load_lds((const __attribute__((address_space(1))) void*)g,
                                   (__attribute__((address_space(3))) void*)l, 16, 0, 0);
}
__device__ __forceinline__ void wg_barrier() {
  asm volatile("" ::: "memory");
  __builtin_amdgcn_s_barrier();
  asm volatile("" ::: "memory");
}
__device__ __forceinline__ void vm_wait4() { asm volatile("s_waitcnt vmcnt(4)" ::: "memory"); }
__device__ __forceinline__ void vm_wait0() { asm volatile("s_waitcnt vmcnt(0)" ::: "memory"); }

// faithful-bug reshape: element (h, i_seg within (seg), d) of head h lives at
// projection row h*512 + seg*64 + (i_seg>>3), col (i_seg&7)*64 + d.
// blk = 0 (Q), 512 (K), 1024 (V) inside the fused qkv row of width 1536.
__device__ __forceinline__ size_t qkv_addr(int b, int h, int seg, int i_seg, int d, int blk) {
  int r = h * 512 + seg * 64 + (i_seg >> 3);
  int c = ((i_seg & 7) << 6) + d;
  return ((size_t)b * S_ + r) * QKVN + blk + c;
}

// ---------------------------------------------------------------------------
__global__ void dtype_probe(const unsigned short* __restrict__ g, int* __restrict__ flag) {
  __shared__ int cnt;
  if (threadIdx.x == 0) cnt = 0;
  __syncthreads();
  int c = 0;
  for (int i = threadIdx.x; i < 1024; i += 256) c += (g[i] == 0x3F80u) ? 1 : 0;
  atomicAdd(&cnt, c);
  __syncthreads();
  if (threadIdx.x == 0) flag[0] = (cnt <= 768) ? 1 : 0;
}

__global__ void convert_small(const void* __restrict__ in, unsigned short* __restrict__ out,
                              int n, const int* __restrict__ flagp) {
  int i = blockIdx.x * 256 + threadIdx.x;
  if (i >= n) return;
  out[i] = (*flagp) ? f2bf(((const float*)in)[i]) : ((const unsigned short*)in)[i];
}

// 8-elem-per-thread flag-aware converter (x -> bf16), vectorized.
__global__ __launch_bounds__(256)
void convert_x(const void* __restrict__ in, unsigned short* __restrict__ out,
               int n8, const int* __restrict__ flagp) {
  int i = blockIdx.x * 256 + threadIdx.x;
  if (i >= n8) return;
  if (*flagp) {
    const f32x4* p = (const f32x4*)in;
    f32x4 a = p[(size_t)i * 2], b = p[(size_t)i * 2 + 1];
    u16x8 o;
    for (int j = 0; j < 4; j++) { o[j] = f2bf(a[j]); o[j + 4] = f2bf(b[j]); }
    *(u16x8*)(out + (size_t)i * 8) = o;
  } else {
    *(u16x8*)(out + (size_t)i * 8) = ((const u16x8*)in)[i];
  }
}

// ---------------------------------------------------------------------------
// Flag-aware [K][N] -> [N][K] transpose to bf16 (32x32 LDS tiles), block (32,8)
// ---------------------------------------------------------------------------
__global__ void transpose_any(const void* __restrict__ in, unsigned short* __restrict__ out,
                              int K, int N, const int* __restrict__ flagp) {
  __shared__ unsigned short tile[32][33];
  const int isf = *flagp;
  int n0 = blockIdx.x * 32, k0 = blockIdx.y * 32;
  int tx = threadIdx.x, ty = threadIdx.y;
  for (int j = 0; j < 4; j++) {
    size_t idx = (size_t)(k0 + ty + j * 8) * N + n0 + tx;
    tile[ty + j * 8][tx] = isf ? f2bf(((const float*)in)[idx]) : ((const unsigned short*)in)[idx];
  }
  __syncthreads();
  for (int j = 0; j < 4; j++)
    out[(size_t)(n0 + ty + j * 8) * K + k0 + tx] = tile[tx][ty + j * 8];
}

// ---------------------------------------------------------------------------
// Main GEMM: 256x256 tile, BK=64, 512 threads (8 waves = 2Mx4N), 8-phase
// schedule, counted vmcnt(4), st-swizzled LDS, XCD-swizzled block id.
// Inner math: v_mfma_f32_32x32x16_bf16. Per wave: 128x64 output = 4x2 tiles
// of 32x32, acc = f32x16[4][2]. Fragments: A row = lane&31 (+mi*32), 8
// contiguous K at (lane>>5)*8 + ks*16; same for B (Bt row = C col). C/D:
// col = lane&31, row = (reg&3) + 8*(reg>>2) + 4*(lane>>5)   [m74/m101].
// C[M][N] = A[M][K] @ Bt[N][K]^T (+bias,+relu). All bf16, f32 accum.
// Requires M%256==0, N%256==0, K%128==0 (K>=256), grid %8==0.
// LDS layout per matrix: [2 buf][2 half][128 rows][64 cols] bf16; within a
// row the 8 16B-chunks are XOR-swizzled by (row&7). global_load_lds writes
// LDS linearly, so the *source* address carries the inverse permutation.
// ---------------------------------------------------------------------------
template <int HAS_BIAS, int RELU>
__global__ __launch_bounds__(512, 2)
void gemm256(const unsigned short* __restrict__ A,
             const unsigned short* __restrict__ Bt,
             const unsigned short* __restrict__ bias,
             unsigned short* __restrict__ C,
             int M, int N, int K) {
  __shared__ unsigned short smem[2][2][2][8192];   // [buf][A/B][half][128*64] = 128 KiB
  const int tid = threadIdx.x;
  const int lane = tid & 63;
  const int w = tid >> 6;                // 0..7
  const int wr = w >> 2, wc = w & 3;     // wave -> (2M x 4N) grid
  const int l31 = lane & 31, kg = lane >> 5;

  // T1: bijective XCD swizzle (all grids here are %8==0)
  const int nbx = N >> 8;
  const int nwg = (M >> 8) * nbx;
  const int orig = blockIdx.x;
  const int swz = (orig & 7) * (nwg >> 3) + (orig >> 3);
  const int m0 = (swz / nbx) << 8, n0 = (swz % nbx) << 8;

  // staging constants: lane covers LDS linear (r = seg*8 + lane>>3, c = lane&7);
  // source chunk = c ^ (r&7) = (lane&7) ^ (lane>>3)
  const int srh = lane >> 3;
  const int sc = ((lane & 7) ^ srh) << 3;   // source col offset (elems)

  unsigned short* const A0p = &smem[0][0][0][0];
  unsigned short* const B0p = &smem[0][1][0][0];
  unsigned short* const A1p = &smem[1][0][0][0];
  unsigned short* const B1p = &smem[1][1][0][0];

  // A half h holds global tile rows {wr*128 + h*64 + 0..63} at local r=wr*64+..
  auto stA = [&](unsigned short* dst, int h, int kt) {
#pragma unroll
    for (int i2 = 0; i2 < 2; i2++) {
      const int seg = (i2 << 3) + w;
      const int r = (seg << 3) + srh;
      const int g = ((r >> 6) << 7) + (h << 6) + (r & 63);
      async_load16(A + (size_t)(m0 + g) * K + (kt << 6) + sc,
                   dst + (h << 13) + (seg << 9));
    }
  };
  // B half h holds Bt rows {wc*64 + h*32 + 0..31} at local r=wc*32+..
  auto stB = [&](unsigned short* dst, int h, int kt) {
#pragma unroll
    for (int i2 = 0; i2 < 2; i2++) {
      const int seg = (i2 << 3) + w;
      const int r = (seg << 3) + srh;
      const int g = ((r >> 5) << 6) + (h << 5) + (r & 31);
      async_load16(Bt + (size_t)(n0 + g) * K + (kt << 6) + sc,
                   dst + (h << 13) + (seg << 9));
    }
  };

  f32x16 acc[4][2] = {};                 // [mi 32-row][ni 32-col] - static idx only
  short8 af[2][4];                       // current mi-pair x ks
  short8 bfr[2][4];                      // both ni x ks (each frag read once)

  // A frags for mi = MP*2 + {0,1}: half MP, local row wr*64 + (mi&1)*32 + l31,
  // chunk = ks*2 + kg, swizzled ^ (r&7).
#define RD_A2(BASE, MP) \
  { _Pragma("unroll") for (int mi2 = 0; mi2 < 2; mi2++) { \
      const int r_ = (wr << 6) + (mi2 << 5) + l31; \
      const unsigned short* p_ = (BASE) + ((MP) << 13) + (r_ << 6); \
      _Pragma("unroll") for (int ks = 0; ks < 4; ks++) { \
        const int ch_ = (ks << 1) + kg; \
        af[mi2][ks] = *(const short8*)(p_ + ((ch_ ^ (r_ & 7)) << 3)); } } }
  // B frags for ni = NH: half NH, local row wc*32 + l31.
#define RD_B1(BASE, NH) \
  { const int r_ = (wc << 5) + l31; \
    const unsigned short* p_ = (BASE) + ((NH) << 13) + (r_ << 6); \
    _Pragma("unroll") for (int ks = 0; ks < 4; ks++) { \
      const int ch_ = (ks << 1) + kg; \
      bfr[NH][ks] = *(const short8*)(p_ + ((ch_ ^ (r_ & 7)) << 3)); } }
#define MFMA_P(MP, NI) \
  { __builtin_amdgcn_s_setprio(1); \
    _Pragma("unroll") for (int ks = 0; ks < 4; ks++) { \
      acc[(MP) * 2 + 0][NI] = __builtin_amdgcn_mfma_f32_32x32x16_bf16(af[0][ks], bfr[NI][ks], acc[(MP) * 2 + 0][NI], 0, 0, 0); \
      acc[(MP) * 2 + 1][NI] = __builtin_amdgcn_mfma_f32_32x32x16_bf16(af[1][ks], bfr[NI][ks], acc[(MP) * 2 + 1][NI], 0, 0, 0); } \
    __builtin_amdgcn_s_setprio(0); }

  // prologue: kt0 all 4 halves first (oldest), then kt1 {A0,B1}.
  // vmcnt(4) -> kt0 fully landed, kt1 {A0,B1} (4 loads) stay in flight.
  stA(A0p, 0, 0); stB(B0p, 1, 0); stA(A0p, 1, 0); stB(B0p, 0, 0);
  stA(A1p, 0, 1); stB(B1p, 1, 1);
  vm_wait4();
  wg_barrier();

  // 8 phases / iteration, 2 K-tiles / iteration. Per tile the 4 phases
  // compute (mi-pair, ni) groups (0,0)(0,1)(1,1)(1,0); each LDS half region
  // is staged the phase after its last read. vmcnt(4) only at phase 4/8.
  const int NI_ = K >> 7;
  for (int i = 0; i < NI_; i++) {
    const int kt = i << 1;
    const bool nx = (i + 1 < NI_);
    // ---- tile kt (buf0) ----
    RD_A2(A0p, 0) RD_B1(B0p, 0)
    stA(A1p, 1, kt + 1);                       // buf1.A1 free since prev p8
    wg_barrier(); MFMA_P(0, 0) wg_barrier();
    RD_B1(B0p, 1)
    stB(B1p, 0, kt + 1);                       // buf1.B0 free since prev p8
    wg_barrier(); MFMA_P(0, 1) wg_barrier();
    RD_A2(A0p, 1)
    if (nx) stA(A0p, 0, kt + 2);               // buf0.A0 last read p1
    wg_barrier(); MFMA_P(1, 1) wg_barrier();
    if (nx) stB(B0p, 1, kt + 2);               // buf0.B1 last read p2
    wg_barrier(); MFMA_P(1, 0)
    if (nx) vm_wait4(); else vm_wait0();       // kt+1 fully landed
    wg_barrier();
    // ---- tile kt+1 (buf1) ----
    RD_A2(A1p, 0) RD_B1(B1p, 0)
    if (nx) stA(A0p, 1, kt + 2);               // buf0.A1 last read p3
    wg_barrier(); MFMA_P(0, 0) wg_barrier();
    RD_B1(B1p, 1)
    if (nx) stB(B0p, 0, kt + 2);               // buf0.B0 last read p1
    wg_barrier(); MFMA_P(0, 1) wg_barrier();
    RD_A2(A1p, 1)
    if (nx) stA(A1p, 0, kt + 3);               // buf1.A0 last read p5
    wg_barrier(); MFMA_P(1, 1) wg_barrier();
    if (nx) stB(B1p, 1, kt + 3);               // buf1.B1 last read p6
    wg_barrier(); MFMA_P(1, 0)
    if (nx) vm_wait4(); else vm_wait0();       // kt+2 fully landed
    wg_barrier();
  }
#undef RD_A2
#undef RD_B1
#undef MFMA_P

  // epilogue: C/D 32x32 layout col = l31, row = (reg&3)+8*(reg>>2)+4*kg
#pragma unroll
  for (int mi = 0; mi < 4; mi++)
#pragma unroll
    for (int ni = 0; ni < 2; ni++) {
      const int col = n0 + (wc << 6) + (ni << 5) + l31;
      const float bv = HAS_BIAS ? bf2f(bias[col]) : 0.f;
      const int rb0 = m0 + (wr << 7) + (mi << 5) + (kg << 2);
#pragma unroll
      for (int reg = 0; reg < 16; reg++) {
        const int row = rb0 + (reg & 3) + ((reg >> 2) << 3);
        float v = acc[mi][ni][reg] + bv;
        if (RELU) v = v > 0.f ? v : 0.f;
        C[(size_t)row * N + col] = f2bf(v);
      }
    }
}

// ---------------------------------------------------------------------------
// Attention pass A: grid (NSEG, H, B). Faithful-reshape addressing via
// qkv_addr. Mseg[(b*H+h)*NSEG+seg][k][v] = sum elu1(K)*V; zseg = sum elu1(K).
// ---------------------------------------------------------------------------
__global__ __launch_bounds__(256)
void attn_stats(const unsigned short* __restrict__ qkv,
                float* __restrict__ Mseg, float* __restrict__ zseg) {
  int seg = blockIdx.x, h = blockIdx.y, b = blockIdx.z;
  __shared__ float sk[64][64];
  __shared__ float sv[64][64];
  int tid = threadIdx.x;
  int kidx = tid >> 2, vg = tid & 3;
  float acc[16] = {};
  float zacc = 0.f;
  for (int c = 0; c < 8; c++) {
    __syncthreads();
    for (int q = 0; q < 2; q++) {
      int cid = tid + q * 256;
      int row = cid >> 3, col = (cid & 7) * 8;
      int i_seg = c * 64 + row;
      u16x8 kv = *(const u16x8*)(qkv + qkv_addr(b, h, seg, i_seg, col, 512));
      u16x8 vv = *(const u16x8*)(qkv + qkv_addr(b, h, seg, i_seg, col, 1024));
      for (int j = 0; j < 8; j++) {
        sk[row][col + j] = elu1(bf2f(kv[j]));
        sv[row][col + j] = bf2f(vv[j]);
      }
    }
    __syncthreads();
    for (int i2 = 0; i2 < 64; i2++) {
      float s = sk[i2][kidx];
      if (vg == 0) zacc += s;
      for (int j = 0; j < 16; j++)
        acc[j] += s * sv[i2][vg * 16 + j];
    }
  }
  size_t ob = ((size_t)b * H_ + h) * NSEG_ + seg;
  float* mp = Mseg + ob * 4096;
  for (int j = 0; j < 16; j++)
    mp[kidx * 64 + vg * 16 + j] = acc[j];
  if (vg == 0) zseg[ob * 64 + kidx] = zacc;
}

// ---------------------------------------------------------------------------
// Attention pass B: grid (B*H). In-place exclusive prefix. mem0=0, z0=1/64.
// ---------------------------------------------------------------------------
__global__ __launch_bounds__(256)
void attn_prefix(float* __restrict__ Mseg, float* __restrict__ zseg) {
  int bh = blockIdx.x, tid = threadIdx.x;
  size_t mb = (size_t)bh * NSEG_ * 4096;
  for (int j = 0; j < 16; j++) {
    int e = tid + j * 256;
    float run = 0.f;
    for (int s = 0; s < NSEG_; s++) {
      float t = Mseg[mb + (size_t)s * 4096 + e];
      Mseg[mb + (size_t)s * 4096 + e] = run;
      run += t;
    }
  }
  if (tid < 64) {
    size_t zb = (size_t)bh * NSEG_ * 64;
    float run = 1.0f / 64.0f;
    for (int s = 0; s < NSEG_; s++) {
      float t = zseg[zb + (size_t)s * 64 + tid];
      zseg[zb + (size_t)s * 64 + tid] = run;
      run += t;
    }
  }
}

// ---------------------------------------------------------------------------
// Attention pass C, MFMA flash-style. grid (8 qtiles, NSEG, H*B), 4 waves.
// ---------------------------------------------------------------------------
__global__ __launch_bounds__(256, 2)
void attn_core(const unsigned short* __restrict__ qkv, const unsigned short* __restrict__ betas_bf,
               const float* __restrict__ Mpre, const float* __restrict__ zpre,
               unsigned short* __restrict__ att) {
  const int t = blockIdx.x, seg = blockIdx.y;
  const int h = blockIdx.z & 7, b = blockIdx.z >> 3;
  __shared__ unsigned short q_lds[64 * 72];
  __shared__ unsigned short sq_lds[64 * 72];
  __shared__ unsigned short k_lds[64 * 72];
  __shared__ unsigned short vt_lds[64 * 72];
  __shared__ unsigned short p_lds[64 * 72];
  __shared__ unsigned short mt_lds[64 * 72];
  __shared__ float z_lds[64];
  __shared__ float den_lds[64];
  const int tid = threadIdx.x, lane = tid & 63, w = tid >> 6;
  const int l15 = lane & 15, quad = lane >> 4;
  size_t sbi = ((size_t)b * H_ + h) * NSEG_ + seg;
  const float* mp = Mpre + sbi * 4096;
  const float* zp = zpre + sbi * 64;

  for (int c = 0; c < 2; c++) {
    int idx = tid + c * 256;
    int row = idx >> 3, d0 = (idx & 7) * 8;
    u16x8 qv = *(const u16x8*)(qkv + qkv_addr(b, h, seg, t * 64 + row, d0, 0));
    u16x8 sv;
    for (int j = 0; j < 8; j++) sv[j] = f2bf(elu1(bf2f(qv[j])));
    *(u16x8*)(q_lds + row * 72 + d0) = qv;
    *(u16x8*)(sq_lds + row * 72 + d0) = sv;
    f32x4 m0 = *(const f32x4*)(mp + row * 64 + d0);
    f32x4 m1 = *(const f32x4*)(mp + row * 64 + d0 + 4);
    for (int j = 0; j < 4; j++) {
      mt_lds[(d0 + j) * 72 + row] = f2bf(m0[j]);
      mt_lds[(d0 + 4 + j) * 72 + row] = f2bf(m1[j]);
    }
  }
  if (tid < 64) z_lds[tid] = zp[tid];
  __syncthreads();
  if (tid < 64) {
    float d = 0.f;
    for (int k = 0; k < 64; k++) d += bf2f(sq_lds[tid * 72 + k]) * z_lds[k];
    den_lds[tid] = d;
  }
  f32x4 macc[4] = {};
  short8 qa0, qa1;
  {
    short8 a0 = *(const short8*)(sq_lds + (w * 16 + l15) * 72 + quad * 8);
    short8 a1 = *(const short8*)(sq_lds + (w * 16 + l15) * 72 + 32 + quad * 8);
    for (int nt = 0; nt < 4; nt++) {
      short8 b0 = *(const short8*)(mt_lds + (nt * 16 + l15) * 72 + quad * 8);
      short8 b1 = *(const short8*)(mt_lds + (nt * 16 + l15) * 72 + 32 + quad * 8);
      macc[nt] = __builtin_amdgcn_mfma_f32_16x16x32_bf16(a0, b0, macc[nt], 0, 0, 0);
      macc[nt] = __builtin_amdgcn_mfma_f32_16x16x32_bf16(a1, b1, macc[nt], 0, 0, 0);
    }
    qa0 = *(const short8*)(q_lds + (w * 16 + l15) * 72 + quad * 8);
    qa1 = *(const short8*)(q_lds + (w * 16 + l15) * 72 + 32 + quad * 8);
  }

  f32x4 oacc[4] = {};
  float lsum[4] = {0.f, 0.f, 0.f, 0.f};
  for (int kt = 0; kt <= t; kt++) {
    __syncthreads();
    for (int c = 0; c < 2; c++) {
      int idx = tid + c * 256;
      int row = idx >> 3, d0 = (idx & 7) * 8;
      u16x8 kv = *(const u16x8*)(qkv + qkv_addr(b, h, seg, kt * 64 + row, d0, 512));
      *(u16x8*)(k_lds + row * 72 + d0) = kv;
      u16x8 vv = *(const u16x8*)(qkv + qkv_addr(b, h, seg, kt * 64 + row, d0, 1024));
      for (int j = 0; j < 8; j++) vt_lds[(d0 + j) * 72 + row] = vv[j];
    }
    __syncthreads();
    float prow[4][4];
    for (int nt = 0; nt < 4; nt++) {
      short8 kb0 = *(const short8*)(k_lds + (nt * 16 + l15) * 72 + quad * 8);
      short8 kb1 = *(const short8*)(k_lds + (nt * 16 + l15) * 72 + 32 + quad * 8);
      f32x4 s = {};
      s = __builtin_amdgcn_mfma_f32_16x16x32_bf16(qa0, kb0, s, 0, 0, 0);
      s = __builtin_amdgcn_mfma_f32_16x16x32_bf16(qa1, kb1, s, 0, 0, 0);
      int jseg = kt * 64 + nt * 16 + l15;
      for (int r = 0; r < 4; r++) {
        int iseg = t * 64 + w * 16 + quad * 4 + r;
        prow[nt][r] = (jseg <= iseg) ? __expf(s[r] * 0.125f) : 0.f;
      }
    }
    for (int r = 0; r < 4; r++) {
      float rp = prow[0][r] + prow[1][r] + prow[2][r] + prow[3][r];
      rp += __shfl_xor(rp, 1); rp += __shfl_xor(rp, 2);
      rp += __shfl_xor(rp, 4); rp += __shfl_xor(rp, 8);
      lsum[r] += rp;
    }
    for (int nt = 0; nt < 4; nt++)
      for (int r = 0; r < 4; r++)
        p_lds[(w * 16 + quad * 4 + r) * 72 + nt * 16 + l15] = f2bf(prow[nt][r]);
    __syncthreads();
    short8 pa0 = *(const short8*)(p_lds + (w * 16 + l15) * 72 + quad * 8);
    short8 pa1 = *(const short8*)(p_lds + (w * 16 + l15) * 72 + 32 + quad * 8);
    for (int nt = 0; nt < 4; nt++) {
      short8 vb0 = *(const short8*)(vt_lds + (nt * 16 + l15) * 72 + quad * 8);
      short8 vb1 = *(const short8*)(vt_lds + (nt * 16 + l15) * 72 + 32 + quad * 8);
      oacc[nt] = __builtin_amdgcn_mfma_f32_16x16x32_bf16(pa0, vb0, oacc[nt], 0, 0, 0);
      oacc[nt] = __builtin_amdgcn_mfma_f32_16x16x32_bf16(pa1, vb1, oacc[nt], 0, 0, 0);
    }
  }
  __syncthreads();
  // output mapping IS the column slice: att[b, s, h*64+v] (reference transpose)
  for (int nt = 0; nt < 4; nt++) {
    int v = nt * 16 + l15;
    float sb = 1.f / (1.f + __expf(-bf2f(betas_bf[h * 64 + v])));
    for (int r = 0; r < 4; r++) {
      int irow = w * 16 + quad * 4 + r;
      float am = macc[nt][r] / den_lds[irow];
      float ad = oacc[nt][r] / lsum[r];
      float o = sb * am + (1.f - sb) * ad;
      size_t orow = (size_t)b * S_ + (size_t)seg * SEG_ + t * 64 + irow;
      att[orow * 512 + h * 64 + v] = f2bf(o);
    }
  }
}

// ---------------------------------------------------------------------------
// Residual + LayerNorm, one wave per row (16 elems/lane, wave-only reduce).
// x2 bf16 ws; x raw (flag dtype); out raw (flag dtype). grid = M/4, block 256.
// ---------------------------------------------------------------------------
__global__ __launch_bounds__(256)
void ln_kernel(const unsigned short* __restrict__ x2, const void* __restrict__ xraw,
               const unsigned short* __restrict__ gamma_bf, const unsigned short* __restrict__ beta_bf,
               void* __restrict__ out, const int* __restrict__ flagp) {
  const int isf = *flagp;
  const int w = threadIdx.x >> 6, lane = threadIdx.x & 63;
  const int row = blockIdx.x * 4 + w;
  const size_t rb = (size_t)row * 1024 + lane * 16;
  u16x8 a0 = *(const u16x8*)(x2 + rb);
  u16x8 a1 = *(const u16x8*)(x2 + rb + 8);
  float xv[16];
  if (isf) {
    const float* xf = (const float*)xraw + rb;
    for (int j = 0; j < 16; j += 4) {
      f32x4 t = *(const f32x4*)(xf + j);
      xv[j] = t[0]; xv[j + 1] = t[1]; xv[j + 2] = t[2]; xv[j + 3] = t[3];
    }
  } else {
    const unsigned short* xu = (const unsigned short*)xraw + rb;
    u16x8 t0 = *(const u16x8*)xu, t1 = *(const u16x8*)(xu + 8);
    for (int j = 0; j < 8; j++) { xv[j] = bf2f(t0[j]); xv[8 + j] = bf2f(t1[j]); }
  }
  float vv[16], s = 0.f, ss = 0.f;
  for (int j = 0; j < 8; j++) {
    vv[j] = bf2f(a0[j]) + xv[j];
    vv[8 + j] = bf2f(a1[j]) + xv[8 + j];
  }
  for (int j = 0; j < 16; j++) { s += vv[j]; ss += vv[j] * vv[j]; }
  for (int off = 32; off >= 1; off >>= 1) { s += __shfl_xor(s, off); ss += __shfl_xor(ss, off); }
  float mean = s * (1.f / 1024.f);
  float var = ss * (1.f / 1024.f) - mean * mean;
  float rs = rsqrtf(var + 1e-5f);
  u16x8 g0 = *(const u16x8*)(gamma_bf + lane * 16);
  u16x8 g1 = *(const u16x8*)(gamma_bf + lane * 16 + 8);
  u16x8 be0 = *(const u16x8*)(beta_bf + lane * 16);
  u16x8 be1 = *(const u16x8*)(beta_bf + lane * 16 + 8);
  if (isf) {
    float* op = (float*)out + rb;
    for (int j = 0; j < 16; j += 4) {
      f32x4 o;
      for (int q = 0; q < 4; q++) {
        int jj = j + q;
        float gg = jj < 8 ? bf2f(g0[jj]) : bf2f(g1[jj - 8]);
        float bb = jj < 8 ? bf2f(be0[jj]) : bf2f(be1[jj - 8]);
        o[q] = (vv[jj] - mean) * rs * gg + bb;
      }
      *(f32x4*)(op + j) = o;
    }
  } else {
    u16x8 o0, o1;
    for (int j = 0; j < 8; j++) {
      o0[j] = f2bf((vv[j] - mean) * rs * bf2f(g0[j]) + bf2f(be0[j]));
      o1[j] = f2bf((vv[8 + j] - mean) * rs * bf2f(g1[j]) + bf2f(be1[j]));
    }
    *(u16x8*)((unsigned short*)out + rb) = o0;
    *(u16x8*)((unsigned short*)out + rb + 8) = o1;
  }
}

// ---------------------------------------------------------------------------
extern "C" void kernel_launch(void* const* d_in, const int* in_sizes, int n_in,
                              void* d_out, int out_size, void* d_ws, size_t ws_size,
                              hipStream_t stream) {
  const void* x     = d_in[0];
  const void* Wq    = d_in[1];
  const void* Wk    = d_in[2];
  const void* Wv    = d_in[3];
  const void* Wo    = d_in[4];
  const void* betas = d_in[5];
  const void* W1    = d_in[6];
  const void* b1    = d_in[7];
  const void* W2    = d_in[8];
  const void* b2    = d_in[9];
  const void* gamma = d_in[10];
  const void* beta  = d_in[11];

  char* ws = (char*)d_ws;
  size_t off = 0;
  auto alloc = [&](size_t bytes) { char* p = ws + off; off += (bytes + 255) & ~(size_t)255; return p; };

  const int M = B_ * S_;                       // 16384
  int* flag = (int*)alloc(256);
  unsigned short* W1T = (unsigned short*)alloc((size_t)4096 * 1024 * 2);   // 8 MiB
  unsigned short* W2T = (unsigned short*)alloc((size_t)1024 * 4096 * 2);   // 8 MiB
  unsigned short* WqkvT = (unsigned short*)alloc((size_t)QKVN * 1024 * 2); // 3 MiB
  unsigned short* WoT = (unsigned short*)alloc((size_t)1024 * 512 * 2);    // 1 MiB
  unsigned short* betas_bf = (unsigned short*)alloc(512 * 2);
  unsigned short* b1_bf    = (unsigned short*)alloc(4096 * 2);
  unsigned short* b2_bf    = (unsigned short*)alloc(1024 * 2);
  unsigned short* gamma_bf = (unsigned short*)alloc(1024 * 2);
  unsigned short* beta_bf  = (unsigned short*)alloc(1024 * 2);
  float* Mseg = (float*)alloc((size_t)B_ * H_ * NSEG_ * 4096 * 4);         // 4 MiB
  float* zseg = (float*)alloc((size_t)B_ * H_ * NSEG_ * 64 * 4);           // 64 KiB
  unsigned short* qkvb = (unsigned short*)alloc((size_t)M * QKVN * 2);     // 48 MiB
  unsigned short* x1   = qkvb;                 // 32 MiB alias (qkv dead after attn)
  unsigned short* xbf  = (unsigned short*)d_out;   // 32 MiB x-as-bf16 (dead before attn out)
  unsigned short* attb = (unsigned short*)d_out;   // 16 MiB in d_out (dead before MLP)
  unsigned short* hsml = (unsigned short*)d_out;   // 64 MiB MLP hidden fallback (dead before LN)

  if (off > ws_size) return;

  // full-M MLP hidden (128 MiB) if workspace allows; else chunked via d_out
  size_t off_save = off;
  unsigned short* hbig = (unsigned short*)alloc((size_t)M * 4096 * 2);     // 128 MiB
  const bool bigws = (off <= ws_size);
  if (!bigws) off = off_save;

  dtype_probe<<<1, 256, 0, stream>>>((const unsigned short*)gamma, flag);
  convert_small<<<2, 256, 0, stream>>>(betas, betas_bf, 512, flag);
  convert_small<<<16, 256, 0, stream>>>(b1, b1_bf, 4096, flag);
  convert_small<<<4, 256, 0, stream>>>(b2, b2_bf, 1024, flag);
  convert_small<<<4, 256, 0, stream>>>(gamma, gamma_bf, 1024, flag);
  convert_small<<<4, 256, 0, stream>>>(beta, beta_bf, 1024, flag);

  dim3 tb(32, 8);
  transpose_any<<<dim3(16, 32), tb, 0, stream>>>(Wq, WqkvT, 1024, 512, flag);
  transpose_any<<<dim3(16, 32), tb, 0, stream>>>(Wk, WqkvT + (size_t)512 * 1024, 1024, 512, flag);
  transpose_any<<<dim3(16, 32), tb, 0, stream>>>(Wv, WqkvT + (size_t)1024 * 1024, 1024, 512, flag);
  transpose_any<<<dim3(32, 16), tb, 0, stream>>>(Wo, WoT, 512, 1024, flag);
  transpose_any<<<dim3(128, 32), tb, 0, stream>>>(W1, W1T, 1024, 4096, flag);
  transpose_any<<<dim3(32, 128), tb, 0, stream>>>(W2, W2T, 4096, 1024, flag);

  // x -> bf16 (in d_out scratch; dead before attn_core writes attb there)
  convert_x<<<dim3((M * 1024 / 8 + 255) / 256), 256, 0, stream>>>(x, xbf, M * 1024 / 8, flag);

  // fused QKV: (16384,1024)@(1024,1536) -> qkvb.  grid 64x6 = 384 blocks
  gemm256<0, 0><<<dim3(384), 512, 0, stream>>>(xbf, WqkvT, nullptr, qkvb, M, QKVN, 1024);

  attn_stats<<<dim3(NSEG_, H_, B_), 256, 0, stream>>>(qkvb, Mseg, zseg);
  attn_prefix<<<dim3(B_ * H_), 256, 0, stream>>>(Mseg, zseg);
  attn_core<<<dim3(8, NSEG_, H_ * B_), 256, 0, stream>>>(qkvb, betas_bf, Mseg, zseg, attb);

  // out proj: (16384,512)@(512,1024) -> x1 (qkv region dead).  grid 256
  gemm256<0, 0><<<dim3(256), 512, 0, stream>>>(attb, WoT, nullptr, x1, M, 1024, 512);

  if (bigws) {
    // full-M MLP: W1 grid 64x16=1024 (4/CU even), W2 grid 64x4=256 (1/CU even)
    gemm256<1, 1><<<dim3(1024), 512, 0, stream>>>(x1, W1T, b1_bf, hbig, M, 4096, 1024);
    gemm256<1, 0><<<dim3(256), 512, 0, stream>>>(hbig, W2T, b2_bf, x1, M, 1024, 4096);
  } else {
    // chunked fallback: hidden (64 MiB) in d_out
    for (int c = 0; c < 2; c++) {
      unsigned short* x1c = x1 + (size_t)c * 8192 * 1024;
      gemm256<1, 1><<<dim3(512), 512, 0, stream>>>(x1c, W1T, b1_bf, hsml, 8192, 4096, 1024);
      gemm256<1, 0><<<dim3(128), 512, 0, stream>>>(hsml, W2T, b2_bf, x1c, 8192, 1024, 4096);
    }
  }

  ln_kernel<<<dim3(M / 4), 256, 0, stream>>>(x1, x, gamma_bf, beta_bf, d_out, flag);
}

// Round 4
// 688.033 us; speedup vs baseline: 1.0576x; 1.0576x over previous
//
#include <hip/hip_runtime.h>

// ---------------------------------------------------------------------------
// InfiniteTransformer on MI355X (gfx950). fp32 I/O (runtime probe keeps bf16
// fallback), bf16 MFMA internals, f32 accum.
// B=4 S=4096 DIM=1024 H=8 DK=DV=64 SEG=512 NSEG=8 EXP=4
// R10: revert gemm256 to the R8 16x16 MFMA version (R9's 32x32 read pattern
// produced 12.6M LDS bank conflicts/dispatch -> net regression). Keep R9's
// wave-per-row ln_kernel. NEW: attn_core K/V staging double-buffered through
// registers (T14 async-STAGE split) - loads for tile kt+1 issued before the
// compute of tile kt, hiding HBM/L2 latency under MFMA+softmax.
// ---------------------------------------------------------------------------

typedef __attribute__((ext_vector_type(8)))  short    short8;   // 8 x bf16 (MFMA A/B frag)
typedef __attribute__((ext_vector_type(4)))  float    f32x4;
typedef __attribute__((ext_vector_type(8)))  unsigned short u16x8;
typedef __attribute__((ext_vector_type(4)))  unsigned short u16x4;

#define B_    4
#define S_    4096
#define H_    8
#define SEG_  512
#define NSEG_ 8
#define QKVN  1536

__device__ __forceinline__ float bf2f(unsigned short u) {
  union { unsigned int i; float f; } x; x.i = ((unsigned int)u) << 16; return x.f;
}
__device__ __forceinline__ unsigned short f2bf(float f) {
  union { float f; unsigned int i; } x; x.f = f;
  unsigned int r = x.i + 0x7FFFu + ((x.i >> 16) & 1u);   // RTNE
  return (unsigned short)(r >> 16);
}
__device__ __forceinline__ float elu1(float x) { return x > 0.f ? x + 1.f : __expf(x); }

__device__ __forceinline__ void async_load16(const unsigned short* g, unsigned short* l) {
  __builtin_amdgcn_global_load_lds((const __attribute__((address_space(1))) void*)g,
                                   (__attribute__((address_space(3))) void*)l, 16, 0, 0);
}
__device__ __forceinline__ void wg_barrier() {
  asm volatile("" ::: "memory");
  __builtin_amdgcn_s_barrier();
  asm volatile("" ::: "memory");
}
__device__ __forceinline__ void vm_wait4() { asm volatile("s_waitcnt vmcnt(4)" ::: "memory"); }
__device__ __forceinline__ void vm_wait0() { asm volatile("s_waitcnt vmcnt(0)" ::: "memory"); }

// faithful-bug reshape: element (h, i_seg within (seg), d) of head h lives at
// projection row h*512 + seg*64 + (i_seg>>3), col (i_seg&7)*64 + d.
// blk = 0 (Q), 512 (K), 1024 (V) inside the fused qkv row of width 1536.
__device__ __forceinline__ size_t qkv_addr(int b, int h, int seg, int i_seg, int d, int blk) {
  int r = h * 512 + seg * 64 + (i_seg >> 3);
  int c = ((i_seg & 7) << 6) + d;
  return ((size_t)b * S_ + r) * QKVN + blk + c;
}

// ---------------------------------------------------------------------------
__global__ void dtype_probe(const unsigned short* __restrict__ g, int* __restrict__ flag) {
  __shared__ int cnt;
  if (threadIdx.x == 0) cnt = 0;
  __syncthreads();
  int c = 0;
  for (int i = threadIdx.x; i < 1024; i += 256) c += (g[i] == 0x3F80u) ? 1 : 0;
  atomicAdd(&cnt, c);
  __syncthreads();
  if (threadIdx.x == 0) flag[0] = (cnt <= 768) ? 1 : 0;
}

__global__ void convert_small(const void* __restrict__ in, unsigned short* __restrict__ out,
                              int n, const int* __restrict__ flagp) {
  int i = blockIdx.x * 256 + threadIdx.x;
  if (i >= n) return;
  out[i] = (*flagp) ? f2bf(((const float*)in)[i]) : ((const unsigned short*)in)[i];
}

// 8-elem-per-thread flag-aware converter (x -> bf16), vectorized.
__global__ __launch_bounds__(256)
void convert_x(const void* __restrict__ in, unsigned short* __restrict__ out,
               int n8, const int* __restrict__ flagp) {
  int i = blockIdx.x * 256 + threadIdx.x;
  if (i >= n8) return;
  if (*flagp) {
    const f32x4* p = (const f32x4*)in;
    f32x4 a = p[(size_t)i * 2], b = p[(size_t)i * 2 + 1];
    u16x8 o;
    for (int j = 0; j < 4; j++) { o[j] = f2bf(a[j]); o[j + 4] = f2bf(b[j]); }
    *(u16x8*)(out + (size_t)i * 8) = o;
  } else {
    *(u16x8*)(out + (size_t)i * 8) = ((const u16x8*)in)[i];
  }
}

// ---------------------------------------------------------------------------
// Flag-aware [K][N] -> [N][K] transpose to bf16 (32x32 LDS tiles), block (32,8)
// ---------------------------------------------------------------------------
__global__ void transpose_any(const void* __restrict__ in, unsigned short* __restrict__ out,
                              int K, int N, const int* __restrict__ flagp) {
  __shared__ unsigned short tile[32][33];
  const int isf = *flagp;
  int n0 = blockIdx.x * 32, k0 = blockIdx.y * 32;
  int tx = threadIdx.x, ty = threadIdx.y;
  for (int j = 0; j < 4; j++) {
    size_t idx = (size_t)(k0 + ty + j * 8) * N + n0 + tx;
    tile[ty + j * 8][tx] = isf ? f2bf(((const float*)in)[idx]) : ((const unsigned short*)in)[idx];
  }
  __syncthreads();
  for (int j = 0; j < 4; j++)
    out[(size_t)(n0 + ty + j * 8) * K + k0 + tx] = tile[tx][ty + j * 8];
}

// ---------------------------------------------------------------------------
// Main GEMM (R8-proven): 256x256 tile, BK=64, 512 threads (8 waves = 2Mx4N),
// 8-phase schedule, counted vmcnt(4), st-swizzled LDS, XCD-swizzled block id.
// Inner math: v_mfma_f32_16x16x32_bf16 (16-row x 4-chunk read pattern is
// bank-conflict-free; the 32x32 variant measured 12.6M conflicts - reverted).
// C[M][N] = A[M][K] @ Bt[N][K]^T (+bias,+relu). All bf16, f32 accum.
// Requires M%256==0, N%256==0, K%128==0 (K>=256), grid %8==0.
// LDS layout per matrix: [2 buf][2 half][128 rows][64 cols] bf16; within a
// row the 8 16B-chunks are XOR-swizzled by (row&7). global_load_lds writes
// LDS linearly, so the *source* address carries the inverse permutation.
// ---------------------------------------------------------------------------
template <int HAS_BIAS, int RELU>
__global__ __launch_bounds__(512, 2)
void gemm256(const unsigned short* __restrict__ A,
             const unsigned short* __restrict__ Bt,
             const unsigned short* __restrict__ bias,
             unsigned short* __restrict__ C,
             int M, int N, int K) {
  __shared__ unsigned short smem[2][2][2][8192];   // [buf][A/B][half][128*64] = 128 KiB
  const int tid = threadIdx.x;
  const int lane = tid & 63;
  const int w = tid >> 6;                // 0..7
  const int wr = w >> 2, wc = w & 3;     // wave -> (2M x 4N) grid
  const int l15 = lane & 15, quad = lane >> 4, l7 = lane & 7;

  // T1: bijective XCD swizzle (all grids here are %8==0)
  const int nbx = N >> 8;
  const int nwg = (M >> 8) * nbx;
  const int orig = blockIdx.x;
  const int swz = (orig & 7) * (nwg >> 3) + (orig >> 3);
  const int m0 = (swz / nbx) << 8, n0 = (swz % nbx) << 8;

  // staging constants: lane covers LDS linear (r = seg*8 + lane>>3, c = lane&7);
  // source chunk = c ^ (r&7) = (lane&7) ^ (lane>>3)
  const int srh = lane >> 3;
  const int sc = ((lane & 7) ^ srh) << 3;   // source col offset (elems)

  unsigned short* const A0p = &smem[0][0][0][0];
  unsigned short* const B0p = &smem[0][1][0][0];
  unsigned short* const A1p = &smem[1][0][0][0];
  unsigned short* const B1p = &smem[1][1][0][0];

  // A half h holds global tile rows {wr*128 + h*64 + 0..63} at local r=wr*64+..
  auto stA = [&](unsigned short* dst, int h, int kt) {
#pragma unroll
    for (int i2 = 0; i2 < 2; i2++) {
      const int seg = (i2 << 3) + w;
      const int r = (seg << 3) + srh;
      const int g = ((r >> 6) << 7) + (h << 6) + (r & 63);
      async_load16(A + (size_t)(m0 + g) * K + (kt << 6) + sc,
                   dst + (h << 13) + (seg << 9));
    }
  };
  // B half h holds Bt rows {wc*64 + h*32 + 0..31} at local r=wc*32+..
  auto stB = [&](unsigned short* dst, int h, int kt) {
#pragma unroll
    for (int i2 = 0; i2 < 2; i2++) {
      const int seg = (i2 << 3) + w;
      const int r = (seg << 3) + srh;
      const int g = ((r >> 5) << 6) + (h << 5) + (r & 31);
      async_load16(Bt + (size_t)(n0 + g) * K + (kt << 6) + sc,
                   dst + (h << 13) + (seg << 9));
    }
  };

  f32x4 acc[2][2][4][2] = {};            // [mh][nh][mi][ni] - static indices only
  short8 af[4][2], bfr[2][2];
  const int arow = (wr << 6) + l15;      // + mi*16
  const int brow = (wc << 5) + l15;      // + ni*16
  const int c0 = (quad ^ l7) << 3;       // swizzled chunk, ks=0
  const int c1 = ((4 + quad) ^ l7) << 3; // swizzled chunk, ks=1

#define RD_A(BASE, MH) \
  { _Pragma("unroll") for (int mi = 0; mi < 4; mi++) { \
      const unsigned short* p_ = (BASE) + ((MH) << 13) + ((arow + mi * 16) << 6); \
      af[mi][0] = *(const short8*)(p_ + c0); \
      af[mi][1] = *(const short8*)(p_ + c1); } }
#define RD_B(BASE, NH) \
  { _Pragma("unroll") for (int ni = 0; ni < 2; ni++) { \
      const unsigned short* p_ = (BASE) + ((NH) << 13) + ((brow + ni * 16) << 6); \
      bfr[ni][0] = *(const short8*)(p_ + c0); \
      bfr[ni][1] = *(const short8*)(p_ + c1); } }
#define MFMA_Q(MH, NH) \
  { __builtin_amdgcn_s_setprio(1); \
    _Pragma("unroll") for (int mi = 0; mi < 4; mi++) \
    _Pragma("unroll") for (int ni = 0; ni < 2; ni++) { \
      acc[MH][NH][mi][ni] = __builtin_amdgcn_mfma_f32_16x16x32_bf16(af[mi][0], bfr[ni][0], acc[MH][NH][mi][ni], 0, 0, 0); \
      acc[MH][NH][mi][ni] = __builtin_amdgcn_mfma_f32_16x16x32_bf16(af[mi][1], bfr[ni][1], acc[MH][NH][mi][ni], 0, 0, 0); } \
    __builtin_amdgcn_s_setprio(0); }

  // prologue: kt0 all 4 halves first (oldest), then kt1 {A0,B1}.
  // vmcnt(4) -> kt0 fully landed, kt1 {A0,B1} (4 loads) stay in flight.
  stA(A0p, 0, 0); stB(B0p, 1, 0); stA(A0p, 1, 0); stB(B0p, 0, 0);
  stA(A1p, 0, 1); stB(B1p, 1, 1);
  vm_wait4();
  wg_barrier();

  // 8 phases / iteration, 2 K-tiles / iteration. Quadrant order per tile:
  // (0,0) (0,1) (1,1) (1,0) -- each half region staged the phase after its
  // last read. vmcnt(4) only at phase 4/8 boundaries (2 halves in flight).
  const int NI = K >> 7;
  for (int i = 0; i < NI; i++) {
    const int kt = i << 1;
    const bool nx = (i + 1 < NI);
    // ---- tile kt (buf0) ----
    RD_A(A0p, 0) RD_B(B0p, 0)
    stA(A1p, 1, kt + 1);                       // buf1.A1 free since prev p8
    wg_barrier(); MFMA_Q(0, 0) wg_barrier();
    RD_B(B0p, 1)
    stB(B1p, 0, kt + 1);                       // buf1.B0 free since prev p8
    wg_barrier(); MFMA_Q(0, 1) wg_barrier();
    RD_A(A0p, 1)
    if (nx) stA(A0p, 0, kt + 2);               // buf0.A0 last read p1
    wg_barrier(); MFMA_Q(1, 1) wg_barrier();
    RD_B(B0p, 0)
    if (nx) stB(B0p, 1, kt + 2);               // buf0.B1 last read p2
    wg_barrier(); MFMA_Q(1, 0)
    if (nx) vm_wait4(); else vm_wait0();       // kt+1 fully landed
    wg_barrier();
    // ---- tile kt+1 (buf1) ----
    RD_A(A1p, 0) RD_B(B1p, 0)
    if (nx) stA(A0p, 1, kt + 2);               // buf0.A1 last read p4
    wg_barrier(); MFMA_Q(0, 0) wg_barrier();
    RD_B(B1p, 1)
    if (nx) stB(B0p, 0, kt + 2);               // buf0.B0 last read p4
    wg_barrier(); MFMA_Q(0, 1) wg_barrier();
    RD_A(A1p, 1)
    if (nx) stA(A1p, 0, kt + 3);               // buf1.A0 last read p6
    wg_barrier(); MFMA_Q(1, 1) wg_barrier();
    RD_B(B1p, 0)
    if (nx) stB(B1p, 1, kt + 3);               // buf1.B1 last read p7
    wg_barrier(); MFMA_Q(1, 0)
    if (nx) vm_wait4(); else vm_wait0();       // kt+2 fully landed
    wg_barrier();
  }
#undef RD_A
#undef RD_B
#undef MFMA_Q

  // epilogue: C/D layout col = l15, row = quad*4 + r
#pragma unroll
  for (int mh = 0; mh < 2; mh++)
#pragma unroll
    for (int nh = 0; nh < 2; nh++)
#pragma unroll
      for (int ni = 0; ni < 2; ni++) {
        const int col = n0 + (wc << 6) + (nh << 5) + (ni << 4) + l15;
        const float bv = HAS_BIAS ? bf2f(bias[col]) : 0.f;
#pragma unroll
        for (int mi = 0; mi < 4; mi++) {
          const int rowb = m0 + (wr << 7) + (mh << 6) + (mi << 4) + (quad << 2);
#pragma unroll
          for (int r = 0; r < 4; r++) {
            float v = acc[mh][nh][mi][ni][r] + bv;
            if (RELU) v = v > 0.f ? v : 0.f;
            C[(size_t)(rowb + r) * N + col] = f2bf(v);
          }
        }
      }
}

// ---------------------------------------------------------------------------
// Attention pass A: grid (NSEG, H, B). Faithful-reshape addressing via
// qkv_addr. Mseg[(b*H+h)*NSEG+seg][k][v] = sum elu1(K)*V; zseg = sum elu1(K).
// ---------------------------------------------------------------------------
__global__ __launch_bounds__(256)
void attn_stats(const unsigned short* __restrict__ qkv,
                float* __restrict__ Mseg, float* __restrict__ zseg) {
  int seg = blockIdx.x, h = blockIdx.y, b = blockIdx.z;
  __shared__ float sk[64][64];
  __shared__ float sv[64][64];
  int tid = threadIdx.x;
  int kidx = tid >> 2, vg = tid & 3;
  float acc[16] = {};
  float zacc = 0.f;
  for (int c = 0; c < 8; c++) {
    __syncthreads();
    for (int q = 0; q < 2; q++) {
      int cid = tid + q * 256;
      int row = cid >> 3, col = (cid & 7) * 8;
      int i_seg = c * 64 + row;
      u16x8 kv = *(const u16x8*)(qkv + qkv_addr(b, h, seg, i_seg, col, 512));
      u16x8 vv = *(const u16x8*)(qkv + qkv_addr(b, h, seg, i_seg, col, 1024));
      for (int j = 0; j < 8; j++) {
        sk[row][col + j] = elu1(bf2f(kv[j]));
        sv[row][col + j] = bf2f(vv[j]);
      }
    }
    __syncthreads();
    for (int i2 = 0; i2 < 64; i2++) {
      float s = sk[i2][kidx];
      if (vg == 0) zacc += s;
      for (int j = 0; j < 16; j++)
        acc[j] += s * sv[i2][vg * 16 + j];
    }
  }
  size_t ob = ((size_t)b * H_ + h) * NSEG_ + seg;
  float* mp = Mseg + ob * 4096;
  for (int j = 0; j < 16; j++)
    mp[kidx * 64 + vg * 16 + j] = acc[j];
  if (vg == 0) zseg[ob * 64 + kidx] = zacc;
}

// ---------------------------------------------------------------------------
// Attention pass B: grid (B*H). In-place exclusive prefix. mem0=0, z0=1/64.
// ---------------------------------------------------------------------------
__global__ __launch_bounds__(256)
void attn_prefix(float* __restrict__ Mseg, float* __restrict__ zseg) {
  int bh = blockIdx.x, tid = threadIdx.x;
  size_t mb = (size_t)bh * NSEG_ * 4096;
  for (int j = 0; j < 16; j++) {
    int e = tid + j * 256;
    float run = 0.f;
    for (int s = 0; s < NSEG_; s++) {
      float t = Mseg[mb + (size_t)s * 4096 + e];
      Mseg[mb + (size_t)s * 4096 + e] = run;
      run += t;
    }
  }
  if (tid < 64) {
    size_t zb = (size_t)bh * NSEG_ * 64;
    float run = 1.0f / 64.0f;
    for (int s = 0; s < NSEG_; s++) {
      float t = zseg[zb + (size_t)s * 64 + tid];
      zseg[zb + (size_t)s * 64 + tid] = run;
      run += t;
    }
  }
}

// ---------------------------------------------------------------------------
// Attention pass C, MFMA flash-style. grid (8 qtiles, NSEG, H*B), 4 waves.
// R10: K/V staging double-buffered through registers (T14): loads for tile
// kt+1 issued right after the LDS writes of tile kt, so the global-load
// latency hides under barrier + QK/softmax/PV compute of tile kt.
// ---------------------------------------------------------------------------
__global__ __launch_bounds__(256, 2)
void attn_core(const unsigned short* __restrict__ qkv, const unsigned short* __restrict__ betas_bf,
               const float* __restrict__ Mpre, const float* __restrict__ zpre,
               unsigned short* __restrict__ att) {
  const int t = blockIdx.x, seg = blockIdx.y;
  const int h = blockIdx.z & 7, b = blockIdx.z >> 3;
  __shared__ unsigned short q_lds[64 * 72];
  __shared__ unsigned short sq_lds[64 * 72];
  __shared__ unsigned short k_lds[64 * 72];
  __shared__ unsigned short vt_lds[64 * 72];
  __shared__ unsigned short p_lds[64 * 72];
  __shared__ unsigned short mt_lds[64 * 72];
  __shared__ float z_lds[64];
  __shared__ float den_lds[64];
  const int tid = threadIdx.x, lane = tid & 63, w = tid >> 6;
  const int l15 = lane & 15, quad = lane >> 4;
  size_t sbi = ((size_t)b * H_ + h) * NSEG_ + seg;
  const float* mp = Mpre + sbi * 4096;
  const float* zp = zpre + sbi * 64;

  // staging geometry (same for both c-chunks)
  const int srow0 = tid >> 3,      sd0 = (tid & 7) * 8;        // c=0
  const int srow1 = (tid + 256) >> 3, sd1 = ((tid + 256) & 7) * 8; // c=1

  for (int c = 0; c < 2; c++) {
    int idx = tid + c * 256;
    int row = idx >> 3, d0 = (idx & 7) * 8;
    u16x8 qv = *(const u16x8*)(qkv + qkv_addr(b, h, seg, t * 64 + row, d0, 0));
    u16x8 sv;
    for (int j = 0; j < 8; j++) sv[j] = f2bf(elu1(bf2f(qv[j])));
    *(u16x8*)(q_lds + row * 72 + d0) = qv;
    *(u16x8*)(sq_lds + row * 72 + d0) = sv;
    f32x4 m0 = *(const f32x4*)(mp + row * 64 + d0);
    f32x4 m1 = *(const f32x4*)(mp + row * 64 + d0 + 4);
    for (int j = 0; j < 4; j++) {
      mt_lds[(d0 + j) * 72 + row] = f2bf(m0[j]);
      mt_lds[(d0 + 4 + j) * 72 + row] = f2bf(m1[j]);
    }
  }
  if (tid < 64) z_lds[tid] = zp[tid];

  // issue K/V loads for kt=0 (in flight across the Q/den setup)
  u16x8 kreg0, kreg1, vreg0, vreg1;
  kreg0 = *(const u16x8*)(qkv + qkv_addr(b, h, seg, srow0, sd0, 512));
  vreg0 = *(const u16x8*)(qkv + qkv_addr(b, h, seg, srow0, sd0, 1024));
  kreg1 = *(const u16x8*)(qkv + qkv_addr(b, h, seg, srow1, sd1, 512));
  vreg1 = *(const u16x8*)(qkv + qkv_addr(b, h, seg, srow1, sd1, 1024));

  __syncthreads();
  if (tid < 64) {
    float d = 0.f;
    for (int k = 0; k < 64; k++) d += bf2f(sq_lds[tid * 72 + k]) * z_lds[k];
    den_lds[tid] = d;
  }
  f32x4 macc[4] = {};
  short8 qa0, qa1;
  {
    short8 a0 = *(const short8*)(sq_lds + (w * 16 + l15) * 72 + quad * 8);
    short8 a1 = *(const short8*)(sq_lds + (w * 16 + l15) * 72 + 32 + quad * 8);
    for (int nt = 0; nt < 4; nt++) {
      short8 b0 = *(const short8*)(mt_lds + (nt * 16 + l15) * 72 + quad * 8);
      short8 b1 = *(const short8*)(mt_lds + (nt * 16 + l15) * 72 + 32 + quad * 8);
      macc[nt] = __builtin_amdgcn_mfma_f32_16x16x32_bf16(a0, b0, macc[nt], 0, 0, 0);
      macc[nt] = __builtin_amdgcn_mfma_f32_16x16x32_bf16(a1, b1, macc[nt], 0, 0, 0);
    }
    qa0 = *(const short8*)(q_lds + (w * 16 + l15) * 72 + quad * 8);
    qa1 = *(const short8*)(q_lds + (w * 16 + l15) * 72 + 32 + quad * 8);
  }

  f32x4 oacc[4] = {};
  float lsum[4] = {0.f, 0.f, 0.f, 0.f};
  for (int kt = 0; kt <= t; kt++) {
    __syncthreads();                      // prev-iter LDS reads done
    // write the buffered tile kt into LDS
    *(u16x8*)(k_lds + srow0 * 72 + sd0) = kreg0;
    *(u16x8*)(k_lds + srow1 * 72 + sd1) = kreg1;
    for (int j = 0; j < 8; j++) {
      vt_lds[(sd0 + j) * 72 + srow0] = vreg0[j];
      vt_lds[(sd1 + j) * 72 + srow1] = vreg1[j];
    }
    // issue loads for kt+1 -- latency hides under barrier + compute below
    if (kt < t) {
      kreg0 = *(const u16x8*)(qkv + qkv_addr(b, h, seg, (kt + 1) * 64 + srow0, sd0, 512));
      vreg0 = *(const u16x8*)(qkv + qkv_addr(b, h, seg, (kt + 1) * 64 + srow0, sd0, 1024));
      kreg1 = *(const u16x8*)(qkv + qkv_addr(b, h, seg, (kt + 1) * 64 + srow1, sd1, 512));
      vreg1 = *(const u16x8*)(qkv + qkv_addr(b, h, seg, (kt + 1) * 64 + srow1, sd1, 1024));
    }
    __syncthreads();
    float prow[4][4];
    for (int nt = 0; nt < 4; nt++) {
      short8 kb0 = *(const short8*)(k_lds + (nt * 16 + l15) * 72 + quad * 8);
      short8 kb1 = *(const short8*)(k_lds + (nt * 16 + l15) * 72 + 32 + quad * 8);
      f32x4 s = {};
      s = __builtin_amdgcn_mfma_f32_16x16x32_bf16(qa0, kb0, s, 0, 0, 0);
      s = __builtin_amdgcn_mfma_f32_16x16x32_bf16(qa1, kb1, s, 0, 0, 0);
      int jseg = kt * 64 + nt * 16 + l15;
      for (int r = 0; r < 4; r++) {
        int iseg = t * 64 + w * 16 + quad * 4 + r;
        prow[nt][r] = (jseg <= iseg) ? __expf(s[r] * 0.125f) : 0.f;
      }
    }
    for (int r = 0; r < 4; r++) {
      float rp = prow[0][r] + prow[1][r] + prow[2][r] + prow[3][r];
      rp += __shfl_xor(rp, 1); rp += __shfl_xor(rp, 2);
      rp += __shfl_xor(rp, 4); rp += __shfl_xor(rp, 8);
      lsum[r] += rp;
    }
    for (int nt = 0; nt < 4; nt++)
      for (int r = 0; r < 4; r++)
        p_lds[(w * 16 + quad * 4 + r) * 72 + nt * 16 + l15] = f2bf(prow[nt][r]);
    __syncthreads();
    short8 pa0 = *(const short8*)(p_lds + (w * 16 + l15) * 72 + quad * 8);
    short8 pa1 = *(const short8*)(p_lds + (w * 16 + l15) * 72 + 32 + quad * 8);
    for (int nt = 0; nt < 4; nt++) {
      short8 vb0 = *(const short8*)(vt_lds + (nt * 16 + l15) * 72 + quad * 8);
      short8 vb1 = *(const short8*)(vt_lds + (nt * 16 + l15) * 72 + 32 + quad * 8);
      oacc[nt] = __builtin_amdgcn_mfma_f32_16x16x32_bf16(pa0, vb0, oacc[nt], 0, 0, 0);
      oacc[nt] = __builtin_amdgcn_mfma_f32_16x16x32_bf16(pa1, vb1, oacc[nt], 0, 0, 0);
    }
  }
  __syncthreads();
  // output mapping IS the column slice: att[b, s, h*64+v] (reference transpose)
  for (int nt = 0; nt < 4; nt++) {
    int v = nt * 16 + l15;
    float sb = 1.f / (1.f + __expf(-bf2f(betas_bf[h * 64 + v])));
    for (int r = 0; r < 4; r++) {
      int irow = w * 16 + quad * 4 + r;
      float am = macc[nt][r] / den_lds[irow];
      float ad = oacc[nt][r] / lsum[r];
      float o = sb * am + (1.f - sb) * ad;
      size_t orow = (size_t)b * S_ + (size_t)seg * SEG_ + t * 64 + irow;
      att[orow * 512 + h * 64 + v] = f2bf(o);
    }
  }
}

// ---------------------------------------------------------------------------
// Residual + LayerNorm, one wave per row (16 elems/lane, wave-only reduce).
// x2 bf16 ws; x raw (flag dtype); out raw (flag dtype). grid = M/4, block 256.
// ---------------------------------------------------------------------------
__global__ __launch_bounds__(256)
void ln_kernel(const unsigned short* __restrict__ x2, const void* __restrict__ xraw,
               const unsigned short* __restrict__ gamma_bf, const unsigned short* __restrict__ beta_bf,
               void* __restrict__ out, const int* __restrict__ flagp) {
  const int isf = *flagp;
  const int w = threadIdx.x >> 6, lane = threadIdx.x & 63;
  const int row = blockIdx.x * 4 + w;
  const size_t rb = (size_t)row * 1024 + lane * 16;
  u16x8 a0 = *(const u16x8*)(x2 + rb);
  u16x8 a1 = *(const u16x8*)(x2 + rb + 8);
  float xv[16];
  if (isf) {
    const float* xf = (const float*)xraw + rb;
    for (int j = 0; j < 16; j += 4) {
      f32x4 t = *(const f32x4*)(xf + j);
      xv[j] = t[0]; xv[j + 1] = t[1]; xv[j + 2] = t[2]; xv[j + 3] = t[3];
    }
  } else {
    const unsigned short* xu = (const unsigned short*)xraw + rb;
    u16x8 t0 = *(const u16x8*)xu, t1 = *(const u16x8*)(xu + 8);
    for (int j = 0; j < 8; j++) { xv[j] = bf2f(t0[j]); xv[8 + j] = bf2f(t1[j]); }
  }
  float vv[16], s = 0.f, ss = 0.f;
  for (int j = 0; j < 8; j++) {
    vv[j] = bf2f(a0[j]) + xv[j];
    vv[8 + j] = bf2f(a1[j]) + xv[8 + j];
  }
  for (int j = 0; j < 16; j++) { s += vv[j]; ss += vv[j] * vv[j]; }
  for (int off = 32; off >= 1; off >>= 1) { s += __shfl_xor(s, off); ss += __shfl_xor(ss, off); }
  float mean = s * (1.f / 1024.f);
  float var = ss * (1.f / 1024.f) - mean * mean;
  float rs = rsqrtf(var + 1e-5f);
  u16x8 g0 = *(const u16x8*)(gamma_bf + lane * 16);
  u16x8 g1 = *(const u16x8*)(gamma_bf + lane * 16 + 8);
  u16x8 be0 = *(const u16x8*)(beta_bf + lane * 16);
  u16x8 be1 = *(const u16x8*)(beta_bf + lane * 16 + 8);
  if (isf) {
    float* op = (float*)out + rb;
    for (int j = 0; j < 16; j += 4) {
      f32x4 o;
      for (int q = 0; q < 4; q++) {
        int jj = j + q;
        float gg = jj < 8 ? bf2f(g0[jj]) : bf2f(g1[jj - 8]);
        float bb = jj < 8 ? bf2f(be0[jj]) : bf2f(be1[jj - 8]);
        o[q] = (vv[jj] - mean) * rs * gg + bb;
      }
      *(f32x4*)(op + j) = o;
    }
  } else {
    u16x8 o0, o1;
    for (int j = 0; j < 8; j++) {
      o0[j] = f2bf((vv[j] - mean) * rs * bf2f(g0[j]) + bf2f(be0[j]));
      o1[j] = f2bf((vv[8 + j] - mean) * rs * bf2f(g1[j]) + bf2f(be1[j]));
    }
    *(u16x8*)((unsigned short*)out + rb) = o0;
    *(u16x8*)((unsigned short*)out + rb + 8) = o1;
  }
}

// ---------------------------------------------------------------------------
extern "C" void kernel_launch(void* const* d_in, const int* in_sizes, int n_in,
                              void* d_out, int out_size, void* d_ws, size_t ws_size,
                              hipStream_t stream) {
  const void* x     = d_in[0];
  const void* Wq    = d_in[1];
  const void* Wk    = d_in[2];
  const void* Wv    = d_in[3];
  const void* Wo    = d_in[4];
  const void* betas = d_in[5];
  const void* W1    = d_in[6];
  const void* b1    = d_in[7];
  const void* W2    = d_in[8];
  const void* b2    = d_in[9];
  const void* gamma = d_in[10];
  const void* beta  = d_in[11];

  char* ws = (char*)d_ws;
  size_t off = 0;
  auto alloc = [&](size_t bytes) { char* p = ws + off; off += (bytes + 255) & ~(size_t)255; return p; };

  const int M = B_ * S_;                       // 16384
  int* flag = (int*)alloc(256);
  unsigned short* W1T = (unsigned short*)alloc((size_t)4096 * 1024 * 2);   // 8 MiB
  unsigned short* W2T = (unsigned short*)alloc((size_t)1024 * 4096 * 2);   // 8 MiB
  unsigned short* WqkvT = (unsigned short*)alloc((size_t)QKVN * 1024 * 2); // 3 MiB
  unsigned short* WoT = (unsigned short*)alloc((size_t)1024 * 512 * 2);    // 1 MiB
  unsigned short* betas_bf = (unsigned short*)alloc(512 * 2);
  unsigned short* b1_bf    = (unsigned short*)alloc(4096 * 2);
  unsigned short* b2_bf    = (unsigned short*)alloc(1024 * 2);
  unsigned short* gamma_bf = (unsigned short*)alloc(1024 * 2);
  unsigned short* beta_bf  = (unsigned short*)alloc(1024 * 2);
  float* Mseg = (float*)alloc((size_t)B_ * H_ * NSEG_ * 4096 * 4);         // 4 MiB
  float* zseg = (float*)alloc((size_t)B_ * H_ * NSEG_ * 64 * 4);           // 64 KiB
  unsigned short* qkvb = (unsigned short*)alloc((size_t)M * QKVN * 2);     // 48 MiB
  unsigned short* x1   = qkvb;                 // 32 MiB alias (qkv dead after attn)
  unsigned short* xbf  = (unsigned short*)d_out;   // 32 MiB x-as-bf16 (dead before attn out)
  unsigned short* attb = (unsigned short*)d_out;   // 16 MiB in d_out (dead before MLP)
  unsigned short* hsml = (unsigned short*)d_out;   // 64 MiB MLP hidden fallback (dead before LN)

  if (off > ws_size) return;

  // full-M MLP hidden (128 MiB) if workspace allows; else chunked via d_out
  size_t off_save = off;
  unsigned short* hbig = (unsigned short*)alloc((size_t)M * 4096 * 2);     // 128 MiB
  const bool bigws = (off <= ws_size);
  if (!bigws) off = off_save;

  dtype_probe<<<1, 256, 0, stream>>>((const unsigned short*)gamma, flag);
  convert_small<<<2, 256, 0, stream>>>(betas, betas_bf, 512, flag);
  convert_small<<<16, 256, 0, stream>>>(b1, b1_bf, 4096, flag);
  convert_small<<<4, 256, 0, stream>>>(b2, b2_bf, 1024, flag);
  convert_small<<<4, 256, 0, stream>>>(gamma, gamma_bf, 1024, flag);
  convert_small<<<4, 256, 0, stream>>>(beta, beta_bf, 1024, flag);

  dim3 tb(32, 8);
  transpose_any<<<dim3(16, 32), tb, 0, stream>>>(Wq, WqkvT, 1024, 512, flag);
  transpose_any<<<dim3(16, 32), tb, 0, stream>>>(Wk, WqkvT + (size_t)512 * 1024, 1024, 512, flag);
  transpose_any<<<dim3(16, 32), tb, 0, stream>>>(Wv, WqkvT + (size_t)1024 * 1024, 1024, 512, flag);
  transpose_any<<<dim3(32, 16), tb, 0, stream>>>(Wo, WoT, 512, 1024, flag);
  transpose_any<<<dim3(128, 32), tb, 0, stream>>>(W1, W1T, 1024, 4096, flag);
  transpose_any<<<dim3(32, 128), tb, 0, stream>>>(W2, W2T, 4096, 1024, flag);

  // x -> bf16 (in d_out scratch; dead before attn_core writes attb there)
  convert_x<<<dim3((M * 1024 / 8 + 255) / 256), 256, 0, stream>>>(x, xbf, M * 1024 / 8, flag);

  // fused QKV: (16384,1024)@(1024,1536) -> qkvb.  grid 64x6 = 384 blocks
  gemm256<0, 0><<<dim3(384), 512, 0, stream>>>(xbf, WqkvT, nullptr, qkvb, M, QKVN, 1024);

  attn_stats<<<dim3(NSEG_, H_, B_), 256, 0, stream>>>(qkvb, Mseg, zseg);
  attn_prefix<<<dim3(B_ * H_), 256, 0, stream>>>(Mseg, zseg);
  attn_core<<<dim3(8, NSEG_, H_ * B_), 256, 0, stream>>>(qkvb, betas_bf, Mseg, zseg, attb);

  // out proj: (16384,512)@(512,1024) -> x1 (qkv region dead).  grid 256
  gemm256<0, 0><<<dim3(256), 512, 0, stream>>>(attb, WoT, nullptr, x1, M, 1024, 512);

  if (bigws) {
    // full-M MLP: W1 grid 64x16=1024 (4/CU even), W2 grid 64x4=256 (1/CU even)
    gemm256<1, 1><<<dim3(1024), 512, 0, stream>>>(x1, W1T, b1_bf, hbig, M, 4096, 1024);
    gemm256<1, 0><<<dim3(256), 512, 0, stream>>>(hbig, W2T, b2_bf, x1, M, 1024, 4096);
  } else {
    // chunked fallback: hidden (64 MiB) in d_out
    for (int c = 0; c < 2; c++) {
      unsigned short* x1c = x1 + (size_t)c * 8192 * 1024;
      gemm256<1, 1><<<dim3(512), 512, 0, stream>>>(x1c, W1T, b1_bf, hsml, 8192, 4096, 1024);
      gemm256<1, 0><<<dim3(128), 512, 0, stream>>>(hsml, W2T, b2_bf, x1c, 8192, 1024, 4096);
    }
  }

  ln_kernel<<<dim3(M / 4), 256, 0, stream>>>(x1, x, gamma_bf, beta_bf, d_out, flag);
}

// Round 5
// 651.882 us; speedup vs baseline: 1.1162x; 1.0555x over previous
//
#include <hip/hip_runtime.h>

// ---------------------------------------------------------------------------
// InfiniteTransformer on MI355X (gfx950). fp32 I/O (runtime probe keeps bf16
// fallback), bf16 MFMA internals, f32 accum.
// B=4 S=4096 DIM=1024 H=8 DK=DV=64 SEG=512 NSEG=8 EXP=4
// R11: gemm256 frozen (R8 16x16 version, 0 conflicts). attn_core LDS aliased
// 6 arrays -> 3 (q/sq/mt dead after setup; k/vt/p live in loop): 56->28 KB,
// occupancy 2->3 blocks/CU. Prep kernels fused: 6 transposes -> 1, 5 small
// converts + convert_x -> 1 (18 -> 11 dispatches).
// ---------------------------------------------------------------------------

typedef __attribute__((ext_vector_type(8)))  short    short8;   // 8 x bf16 (MFMA A/B frag)
typedef __attribute__((ext_vector_type(4)))  float    f32x4;
typedef __attribute__((ext_vector_type(8)))  unsigned short u16x8;
typedef __attribute__((ext_vector_type(4)))  unsigned short u16x4;

#define B_    4
#define S_    4096
#define H_    8
#define SEG_  512
#define NSEG_ 8
#define QKVN  1536

__device__ __forceinline__ float bf2f(unsigned short u) {
  union { unsigned int i; float f; } x; x.i = ((unsigned int)u) << 16; return x.f;
}
__device__ __forceinline__ unsigned short f2bf(float f) {
  union { float f; unsigned int i; } x; x.f = f;
  unsigned int r = x.i + 0x7FFFu + ((x.i >> 16) & 1u);   // RTNE
  return (unsigned short)(r >> 16);
}
__device__ __forceinline__ float elu1(float x) { return x > 0.f ? x + 1.f : __expf(x); }

__device__ __forceinline__ void async_load16(const unsigned short* g, unsigned short* l) {
  __builtin_amdgcn_global_load_lds((const __attribute__((address_space(1))) void*)g,
                                   (__attribute__((address_space(3))) void*)l, 16, 0, 0);
}
__device__ __forceinline__ void wg_barrier() {
  asm volatile("" ::: "memory");
  __builtin_amdgcn_s_barrier();
  asm volatile("" ::: "memory");
}
__device__ __forceinline__ void vm_wait4() { asm volatile("s_waitcnt vmcnt(4)" ::: "memory"); }
__device__ __forceinline__ void vm_wait0() { asm volatile("s_waitcnt vmcnt(0)" ::: "memory"); }

// faithful-bug reshape: element (h, i_seg within (seg), d) of head h lives at
// projection row h*512 + seg*64 + (i_seg>>3), col (i_seg&7)*64 + d.
// blk = 0 (Q), 512 (K), 1024 (V) inside the fused qkv row of width 1536.
__device__ __forceinline__ size_t qkv_addr(int b, int h, int seg, int i_seg, int d, int blk) {
  int r = h * 512 + seg * 64 + (i_seg >> 3);
  int c = ((i_seg & 7) << 6) + d;
  return ((size_t)b * S_ + r) * QKVN + blk + c;
}

// ---------------------------------------------------------------------------
__global__ void dtype_probe(const unsigned short* __restrict__ g, int* __restrict__ flag) {
  __shared__ int cnt;
  if (threadIdx.x == 0) cnt = 0;
  __syncthreads();
  int c = 0;
  for (int i = threadIdx.x; i < 1024; i += 256) c += (g[i] == 0x3F80u) ? 1 : 0;
  atomicAdd(&cnt, c);
  __syncthreads();
  if (threadIdx.x == 0) flag[0] = (cnt <= 768) ? 1 : 0;
}

// ---------------------------------------------------------------------------
// Fused converter: blocks 0..29 handle the 5 small params (7680 elems);
// blocks 30.. handle x -> bf16 (8 elems/thread, vectorized).
// ---------------------------------------------------------------------------
__global__ __launch_bounds__(256)
void convert_all(const void* __restrict__ betas, const void* __restrict__ b1,
                 const void* __restrict__ b2, const void* __restrict__ gamma,
                 const void* __restrict__ beta, const void* __restrict__ x,
                 unsigned short* __restrict__ betas_bf, unsigned short* __restrict__ b1_bf,
                 unsigned short* __restrict__ b2_bf, unsigned short* __restrict__ gamma_bf,
                 unsigned short* __restrict__ beta_bf, unsigned short* __restrict__ xbf,
                 const int* __restrict__ flagp) {
  const int isf = *flagp;
  const int bid = blockIdx.x;
  if (bid < 30) {
    int i = bid * 256 + threadIdx.x;
    const void* in; unsigned short* out; int lo;
    if (i < 512)       { in = betas; out = betas_bf; lo = i; }
    else if (i < 4608) { in = b1;    out = b1_bf;    lo = i - 512; }
    else if (i < 5632) { in = b2;    out = b2_bf;    lo = i - 4608; }
    else if (i < 6656) { in = gamma; out = gamma_bf; lo = i - 5632; }
    else if (i < 7680) { in = beta;  out = beta_bf;  lo = i - 6656; }
    else return;
    out[lo] = isf ? f2bf(((const float*)in)[lo]) : ((const unsigned short*)in)[lo];
  } else {
    int i = (bid - 30) * 256 + threadIdx.x;      // < 2,097,152 (16384*1024/8)
    if (isf) {
      const f32x4* p = (const f32x4*)x;
      f32x4 a = p[(size_t)i * 2], b = p[(size_t)i * 2 + 1];
      u16x8 o;
      for (int j = 0; j < 4; j++) { o[j] = f2bf(a[j]); o[j + 4] = f2bf(b[j]); }
      *(u16x8*)(xbf + (size_t)i * 8) = o;
    } else {
      *(u16x8*)(xbf + (size_t)i * 8) = ((const u16x8*)x)[i];
    }
  }
}

// ---------------------------------------------------------------------------
// Fused flag-aware [K][N] -> [N][K] transposes to bf16 (32x32 LDS tiles),
// block (32,8). One dispatch covers all 6 weight matrices via tile-id ranges.
// ---------------------------------------------------------------------------
__global__ void transpose_all(const void* __restrict__ Wq, const void* __restrict__ Wk,
                              const void* __restrict__ Wv, const void* __restrict__ Wo,
                              const void* __restrict__ W1, const void* __restrict__ W2,
                              unsigned short* __restrict__ WqkvT, unsigned short* __restrict__ WoT,
                              unsigned short* __restrict__ W1T, unsigned short* __restrict__ W2T,
                              const int* __restrict__ flagp) {
  __shared__ unsigned short tile[32][33];
  const int isf = *flagp;
  const int id = blockIdx.x;
  const void* in; unsigned short* out; int K, N, txt, loc;
  if (id < 512)       { in = Wq; out = WqkvT;                          K = 1024; N = 512;  txt = 16;  loc = id; }
  else if (id < 1024) { in = Wk; out = WqkvT + (size_t)512 * 1024;     K = 1024; N = 512;  txt = 16;  loc = id - 512; }
  else if (id < 1536) { in = Wv; out = WqkvT + (size_t)1024 * 1024;    K = 1024; N = 512;  txt = 16;  loc = id - 1024; }
  else if (id < 2048) { in = Wo; out = WoT;                            K = 512;  N = 1024; txt = 32;  loc = id - 1536; }
  else if (id < 6144) { in = W1; out = W1T;                            K = 1024; N = 4096; txt = 128; loc = id - 2048; }
  else                { in = W2; out = W2T;                            K = 4096; N = 1024; txt = 32;  loc = id - 6144; }
  const int n0 = (loc % txt) * 32, k0 = (loc / txt) * 32;
  const int tx = threadIdx.x, ty = threadIdx.y;
  for (int j = 0; j < 4; j++) {
    size_t idx = (size_t)(k0 + ty + j * 8) * N + n0 + tx;
    tile[ty + j * 8][tx] = isf ? f2bf(((const float*)in)[idx]) : ((const unsigned short*)in)[idx];
  }
  __syncthreads();
  for (int j = 0; j < 4; j++)
    out[(size_t)(n0 + ty + j * 8) * K + k0 + tx] = tile[tx][ty + j * 8];
}

// ---------------------------------------------------------------------------
// Main GEMM (R8-proven, frozen): 256x256 tile, BK=64, 512 threads (8 waves),
// 8-phase schedule, counted vmcnt(4), st-swizzled LDS, XCD-swizzled block id.
// v_mfma_f32_16x16x32_bf16 (16-row x 4-chunk reads: bank-conflict-free).
// C[M][N] = A[M][K] @ Bt[N][K]^T (+bias,+relu). All bf16, f32 accum.
// Requires M%256==0, N%256==0, K%128==0 (K>=256), grid %8==0.
// ---------------------------------------------------------------------------
template <int HAS_BIAS, int RELU>
__global__ __launch_bounds__(512, 2)
void gemm256(const unsigned short* __restrict__ A,
             const unsigned short* __restrict__ Bt,
             const unsigned short* __restrict__ bias,
             unsigned short* __restrict__ C,
             int M, int N, int K) {
  __shared__ unsigned short smem[2][2][2][8192];   // [buf][A/B][half][128*64] = 128 KiB
  const int tid = threadIdx.x;
  const int lane = tid & 63;
  const int w = tid >> 6;                // 0..7
  const int wr = w >> 2, wc = w & 3;     // wave -> (2M x 4N) grid
  const int l15 = lane & 15, quad = lane >> 4, l7 = lane & 7;

  // T1: bijective XCD swizzle (all grids here are %8==0)
  const int nbx = N >> 8;
  const int nwg = (M >> 8) * nbx;
  const int orig = blockIdx.x;
  const int swz = (orig & 7) * (nwg >> 3) + (orig >> 3);
  const int m0 = (swz / nbx) << 8, n0 = (swz % nbx) << 8;

  // staging constants: lane covers LDS linear (r = seg*8 + lane>>3, c = lane&7);
  // source chunk = c ^ (r&7) = (lane&7) ^ (lane>>3)
  const int srh = lane >> 3;
  const int sc = ((lane & 7) ^ srh) << 3;   // source col offset (elems)

  unsigned short* const A0p = &smem[0][0][0][0];
  unsigned short* const B0p = &smem[0][1][0][0];
  unsigned short* const A1p = &smem[1][0][0][0];
  unsigned short* const B1p = &smem[1][1][0][0];

  // A half h holds global tile rows {wr*128 + h*64 + 0..63} at local r=wr*64+..
  auto stA = [&](unsigned short* dst, int h, int kt) {
#pragma unroll
    for (int i2 = 0; i2 < 2; i2++) {
      const int seg = (i2 << 3) + w;
      const int r = (seg << 3) + srh;
      const int g = ((r >> 6) << 7) + (h << 6) + (r & 63);
      async_load16(A + (size_t)(m0 + g) * K + (kt << 6) + sc,
                   dst + (h << 13) + (seg << 9));
    }
  };
  // B half h holds Bt rows {wc*64 + h*32 + 0..31} at local r=wc*32+..
  auto stB = [&](unsigned short* dst, int h, int kt) {
#pragma unroll
    for (int i2 = 0; i2 < 2; i2++) {
      const int seg = (i2 << 3) + w;
      const int r = (seg << 3) + srh;
      const int g = ((r >> 5) << 6) + (h << 5) + (r & 31);
      async_load16(Bt + (size_t)(n0 + g) * K + (kt << 6) + sc,
                   dst + (h << 13) + (seg << 9));
    }
  };

  f32x4 acc[2][2][4][2] = {};            // [mh][nh][mi][ni] - static indices only
  short8 af[4][2], bfr[2][2];
  const int arow = (wr << 6) + l15;      // + mi*16
  const int brow = (wc << 5) + l15;      // + ni*16
  const int c0 = (quad ^ l7) << 3;       // swizzled chunk, ks=0
  const int c1 = ((4 + quad) ^ l7) << 3; // swizzled chunk, ks=1

#define RD_A(BASE, MH) \
  { _Pragma("unroll") for (int mi = 0; mi < 4; mi++) { \
      const unsigned short* p_ = (BASE) + ((MH) << 13) + ((arow + mi * 16) << 6); \
      af[mi][0] = *(const short8*)(p_ + c0); \
      af[mi][1] = *(const short8*)(p_ + c1); } }
#define RD_B(BASE, NH) \
  { _Pragma("unroll") for (int ni = 0; ni < 2; ni++) { \
      const unsigned short* p_ = (BASE) + ((NH) << 13) + ((brow + ni * 16) << 6); \
      bfr[ni][0] = *(const short8*)(p_ + c0); \
      bfr[ni][1] = *(const short8*)(p_ + c1); } }
#define MFMA_Q(MH, NH) \
  { __builtin_amdgcn_s_setprio(1); \
    _Pragma("unroll") for (int mi = 0; mi < 4; mi++) \
    _Pragma("unroll") for (int ni = 0; ni < 2; ni++) { \
      acc[MH][NH][mi][ni] = __builtin_amdgcn_mfma_f32_16x16x32_bf16(af[mi][0], bfr[ni][0], acc[MH][NH][mi][ni], 0, 0, 0); \
      acc[MH][NH][mi][ni] = __builtin_amdgcn_mfma_f32_16x16x32_bf16(af[mi][1], bfr[ni][1], acc[MH][NH][mi][ni], 0, 0, 0); } \
    __builtin_amdgcn_s_setprio(0); }

  // prologue: kt0 all 4 halves first (oldest), then kt1 {A0,B1}.
  stA(A0p, 0, 0); stB(B0p, 1, 0); stA(A0p, 1, 0); stB(B0p, 0, 0);
  stA(A1p, 0, 1); stB(B1p, 1, 1);
  vm_wait4();
  wg_barrier();

  const int NI = K >> 7;
  for (int i = 0; i < NI; i++) {
    const int kt = i << 1;
    const bool nx = (i + 1 < NI);
    // ---- tile kt (buf0) ----
    RD_A(A0p, 0) RD_B(B0p, 0)
    stA(A1p, 1, kt + 1);
    wg_barrier(); MFMA_Q(0, 0) wg_barrier();
    RD_B(B0p, 1)
    stB(B1p, 0, kt + 1);
    wg_barrier(); MFMA_Q(0, 1) wg_barrier();
    RD_A(A0p, 1)
    if (nx) stA(A0p, 0, kt + 2);
    wg_barrier(); MFMA_Q(1, 1) wg_barrier();
    RD_B(B0p, 0)
    if (nx) stB(B0p, 1, kt + 2);
    wg_barrier(); MFMA_Q(1, 0)
    if (nx) vm_wait4(); else vm_wait0();
    wg_barrier();
    // ---- tile kt+1 (buf1) ----
    RD_A(A1p, 0) RD_B(B1p, 0)
    if (nx) stA(A0p, 1, kt + 2);
    wg_barrier(); MFMA_Q(0, 0) wg_barrier();
    RD_B(B1p, 1)
    if (nx) stB(B0p, 0, kt + 2);
    wg_barrier(); MFMA_Q(0, 1) wg_barrier();
    RD_A(A1p, 1)
    if (nx) stA(A1p, 0, kt + 3);
    wg_barrier(); MFMA_Q(1, 1) wg_barrier();
    RD_B(B1p, 0)
    if (nx) stB(B1p, 1, kt + 3);
    wg_barrier(); MFMA_Q(1, 0)
    if (nx) vm_wait4(); else vm_wait0();
    wg_barrier();
  }
#undef RD_A
#undef RD_B
#undef MFMA_Q

  // epilogue: C/D layout col = l15, row = quad*4 + r
#pragma unroll
  for (int mh = 0; mh < 2; mh++)
#pragma unroll
    for (int nh = 0; nh < 2; nh++)
#pragma unroll
      for (int ni = 0; ni < 2; ni++) {
        const int col = n0 + (wc << 6) + (nh << 5) + (ni << 4) + l15;
        const float bv = HAS_BIAS ? bf2f(bias[col]) : 0.f;
#pragma unroll
        for (int mi = 0; mi < 4; mi++) {
          const int rowb = m0 + (wr << 7) + (mh << 6) + (mi << 4) + (quad << 2);
#pragma unroll
          for (int r = 0; r < 4; r++) {
            float v = acc[mh][nh][mi][ni][r] + bv;
            if (RELU) v = v > 0.f ? v : 0.f;
            C[(size_t)(rowb + r) * N + col] = f2bf(v);
          }
        }
      }
}

// ---------------------------------------------------------------------------
// Attention pass A: grid (NSEG, H, B). Faithful-reshape addressing via
// qkv_addr. Mseg[(b*H+h)*NSEG+seg][k][v] = sum elu1(K)*V; zseg = sum elu1(K).
// ---------------------------------------------------------------------------
__global__ __launch_bounds__(256)
void attn_stats(const unsigned short* __restrict__ qkv,
                float* __restrict__ Mseg, float* __restrict__ zseg) {
  int seg = blockIdx.x, h = blockIdx.y, b = blockIdx.z;
  __shared__ float sk[64][64];
  __shared__ float sv[64][64];
  int tid = threadIdx.x;
  int kidx = tid >> 2, vg = tid & 3;
  float acc[16] = {};
  float zacc = 0.f;
  for (int c = 0; c < 8; c++) {
    __syncthreads();
    for (int q = 0; q < 2; q++) {
      int cid = tid + q * 256;
      int row = cid >> 3, col = (cid & 7) * 8;
      int i_seg = c * 64 + row;
      u16x8 kv = *(const u16x8*)(qkv + qkv_addr(b, h, seg, i_seg, col, 512));
      u16x8 vv = *(const u16x8*)(qkv + qkv_addr(b, h, seg, i_seg, col, 1024));
      for (int j = 0; j < 8; j++) {
        sk[row][col + j] = elu1(bf2f(kv[j]));
        sv[row][col + j] = bf2f(vv[j]);
      }
    }
    __syncthreads();
    for (int i2 = 0; i2 < 64; i2++) {
      float s = sk[i2][kidx];
      if (vg == 0) zacc += s;
      for (int j = 0; j < 16; j++)
        acc[j] += s * sv[i2][vg * 16 + j];
    }
  }
  size_t ob = ((size_t)b * H_ + h) * NSEG_ + seg;
  float* mp = Mseg + ob * 4096;
  for (int j = 0; j < 16; j++)
    mp[kidx * 64 + vg * 16 + j] = acc[j];
  if (vg == 0) zseg[ob * 64 + kidx] = zacc;
}

// ---------------------------------------------------------------------------
// Attention pass B: grid (B*H). In-place exclusive prefix. mem0=0, z0=1/64.
// ---------------------------------------------------------------------------
__global__ __launch_bounds__(256)
void attn_prefix(float* __restrict__ Mseg, float* __restrict__ zseg) {
  int bh = blockIdx.x, tid = threadIdx.x;
  size_t mb = (size_t)bh * NSEG_ * 4096;
  for (int j = 0; j < 16; j++) {
    int e = tid + j * 256;
    float run = 0.f;
    for (int s = 0; s < NSEG_; s++) {
      float t = Mseg[mb + (size_t)s * 4096 + e];
      Mseg[mb + (size_t)s * 4096 + e] = run;
      run += t;
    }
  }
  if (tid < 64) {
    size_t zb = (size_t)bh * NSEG_ * 64;
    float run = 1.0f / 64.0f;
    for (int s = 0; s < NSEG_; s++) {
      float t = zseg[zb + (size_t)s * 64 + tid];
      zseg[zb + (size_t)s * 64 + tid] = run;
      run += t;
    }
  }
}

// ---------------------------------------------------------------------------
// Attention pass C, MFMA flash-style. grid (8 qtiles, NSEG, H*B), 4 waves.
// R11: LDS aliased to 3 buffers (q->k, sq->vt, mt->p across the setup/loop
// boundary; transitions guarded by existing barriers): 56 -> 28 KB, 3 blk/CU.
// R10's K/V register double-buffer (T14) retained.
// ---------------------------------------------------------------------------
__global__ __launch_bounds__(256, 3)
void attn_core(const unsigned short* __restrict__ qkv, const unsigned short* __restrict__ betas_bf,
               const float* __restrict__ Mpre, const float* __restrict__ zpre,
               unsigned short* __restrict__ att) {
  const int t = blockIdx.x, seg = blockIdx.y;
  const int h = blockIdx.z & 7, b = blockIdx.z >> 3;
  __shared__ unsigned short bufA[64 * 72];   // q_lds  (setup) -> k_lds  (loop)
  __shared__ unsigned short bufB[64 * 72];   // sq_lds (setup) -> vt_lds (loop)
  __shared__ unsigned short bufC[64 * 72];   // mt_lds (setup) -> p_lds  (loop)
  __shared__ float z_lds[64];
  __shared__ float den_lds[64];
  unsigned short* const q_lds = bufA;
  unsigned short* const sq_lds = bufB;
  unsigned short* const mt_lds = bufC;
  unsigned short* const k_lds = bufA;
  unsigned short* const vt_lds = bufB;
  unsigned short* const p_lds = bufC;
  const int tid = threadIdx.x, lane = tid & 63, w = tid >> 6;
  const int l15 = lane & 15, quad = lane >> 4;
  size_t sbi = ((size_t)b * H_ + h) * NSEG_ + seg;
  const float* mp = Mpre + sbi * 4096;
  const float* zp = zpre + sbi * 64;

  // staging geometry (same for both c-chunks)
  const int srow0 = tid >> 3,         sd0 = (tid & 7) * 8;          // c=0
  const int srow1 = (tid + 256) >> 3, sd1 = ((tid + 256) & 7) * 8;  // c=1

  for (int c = 0; c < 2; c++) {
    int idx = tid + c * 256;
    int row = idx >> 3, d0 = (idx & 7) * 8;
    u16x8 qv = *(const u16x8*)(qkv + qkv_addr(b, h, seg, t * 64 + row, d0, 0));
    u16x8 sv;
    for (int j = 0; j < 8; j++) sv[j] = f2bf(elu1(bf2f(qv[j])));
    *(u16x8*)(q_lds + row * 72 + d0) = qv;
    *(u16x8*)(sq_lds + row * 72 + d0) = sv;
    f32x4 m0 = *(const f32x4*)(mp + row * 64 + d0);
    f32x4 m1 = *(const f32x4*)(mp + row * 64 + d0 + 4);
    for (int j = 0; j < 4; j++) {
      mt_lds[(d0 + j) * 72 + row] = f2bf(m0[j]);
      mt_lds[(d0 + 4 + j) * 72 + row] = f2bf(m1[j]);
    }
  }
  if (tid < 64) z_lds[tid] = zp[tid];

  // issue K/V loads for kt=0 (in flight across the Q/den setup)
  u16x8 kreg0, kreg1, vreg0, vreg1;
  kreg0 = *(const u16x8*)(qkv + qkv_addr(b, h, seg, srow0, sd0, 512));
  vreg0 = *(const u16x8*)(qkv + qkv_addr(b, h, seg, srow0, sd0, 1024));
  kreg1 = *(const u16x8*)(qkv + qkv_addr(b, h, seg, srow1, sd1, 512));
  vreg1 = *(const u16x8*)(qkv + qkv_addr(b, h, seg, srow1, sd1, 1024));

  __syncthreads();
  if (tid < 64) {
    float d = 0.f;
    for (int k = 0; k < 64; k++) d += bf2f(sq_lds[tid * 72 + k]) * z_lds[k];
    den_lds[tid] = d;
  }
  f32x4 macc[4] = {};
  short8 qa0, qa1;
  {
    short8 a0 = *(const short8*)(sq_lds + (w * 16 + l15) * 72 + quad * 8);
    short8 a1 = *(const short8*)(sq_lds + (w * 16 + l15) * 72 + 32 + quad * 8);
    for (int nt = 0; nt < 4; nt++) {
      short8 b0 = *(const short8*)(mt_lds + (nt * 16 + l15) * 72 + quad * 8);
      short8 b1 = *(const short8*)(mt_lds + (nt * 16 + l15) * 72 + 32 + quad * 8);
      macc[nt] = __builtin_amdgcn_mfma_f32_16x16x32_bf16(a0, b0, macc[nt], 0, 0, 0);
      macc[nt] = __builtin_amdgcn_mfma_f32_16x16x32_bf16(a1, b1, macc[nt], 0, 0, 0);
    }
    qa0 = *(const short8*)(q_lds + (w * 16 + l15) * 72 + quad * 8);
    qa1 = *(const short8*)(q_lds + (w * 16 + l15) * 72 + 32 + quad * 8);
  }

  f32x4 oacc[4] = {};
  float lsum[4] = {0.f, 0.f, 0.f, 0.f};
  for (int kt = 0; kt <= t; kt++) {
    __syncthreads();                      // prev-iter LDS reads (and setup) done
    // write the buffered tile kt into LDS
    *(u16x8*)(k_lds + srow0 * 72 + sd0) = kreg0;
    *(u16x8*)(k_lds + srow1 * 72 + sd1) = kreg1;
    for (int j = 0; j < 8; j++) {
      vt_lds[(sd0 + j) * 72 + srow0] = vreg0[j];
      vt_lds[(sd1 + j) * 72 + srow1] = vreg1[j];
    }
    // issue loads for kt+1 -- latency hides under barrier + compute below
    if (kt < t) {
      kreg0 = *(const u16x8*)(qkv + qkv_addr(b, h, seg, (kt + 1) * 64 + srow0, sd0, 512));
      vreg0 = *(const u16x8*)(qkv + qkv_addr(b, h, seg, (kt + 1) * 64 + srow0, sd0, 1024));
      kreg1 = *(const u16x8*)(qkv + qkv_addr(b, h, seg, (kt + 1) * 64 + srow1, sd1, 512));
      vreg1 = *(const u16x8*)(qkv + qkv_addr(b, h, seg, (kt + 1) * 64 + srow1, sd1, 1024));
    }
    __syncthreads();
    float prow[4][4];
    for (int nt = 0; nt < 4; nt++) {
      short8 kb0 = *(const short8*)(k_lds + (nt * 16 + l15) * 72 + quad * 8);
      short8 kb1 = *(const short8*)(k_lds + (nt * 16 + l15) * 72 + 32 + quad * 8);
      f32x4 s = {};
      s = __builtin_amdgcn_mfma_f32_16x16x32_bf16(qa0, kb0, s, 0, 0, 0);
      s = __builtin_amdgcn_mfma_f32_16x16x32_bf16(qa1, kb1, s, 0, 0, 0);
      int jseg = kt * 64 + nt * 16 + l15;
      for (int r = 0; r < 4; r++) {
        int iseg = t * 64 + w * 16 + quad * 4 + r;
        prow[nt][r] = (jseg <= iseg) ? __expf(s[r] * 0.125f) : 0.f;
      }
    }
    for (int r = 0; r < 4; r++) {
      float rp = prow[0][r] + prow[1][r] + prow[2][r] + prow[3][r];
      rp += __shfl_xor(rp, 1); rp += __shfl_xor(rp, 2);
      rp += __shfl_xor(rp, 4); rp += __shfl_xor(rp, 8);
      lsum[r] += rp;
    }
    for (int nt = 0; nt < 4; nt++)
      for (int r = 0; r < 4; r++)
        p_lds[(w * 16 + quad * 4 + r) * 72 + nt * 16 + l15] = f2bf(prow[nt][r]);
    __syncthreads();
    short8 pa0 = *(const short8*)(p_lds + (w * 16 + l15) * 72 + quad * 8);
    short8 pa1 = *(const short8*)(p_lds + (w * 16 + l15) * 72 + 32 + quad * 8);
    for (int nt = 0; nt < 4; nt++) {
      short8 vb0 = *(const short8*)(vt_lds + (nt * 16 + l15) * 72 + quad * 8);
      short8 vb1 = *(const short8*)(vt_lds + (nt * 16 + l15) * 72 + 32 + quad * 8);
      oacc[nt] = __builtin_amdgcn_mfma_f32_16x16x32_bf16(pa0, vb0, oacc[nt], 0, 0, 0);
      oacc[nt] = __builtin_amdgcn_mfma_f32_16x16x32_bf16(pa1, vb1, oacc[nt], 0, 0, 0);
    }
  }
  __syncthreads();
  // output mapping IS the column slice: att[b, s, h*64+v] (reference transpose)
  for (int nt = 0; nt < 4; nt++) {
    int v = nt * 16 + l15;
    float sb = 1.f / (1.f + __expf(-bf2f(betas_bf[h * 64 + v])));
    for (int r = 0; r < 4; r++) {
      int irow = w * 16 + quad * 4 + r;
      float am = macc[nt][r] / den_lds[irow];
      float ad = oacc[nt][r] / lsum[r];
      float o = sb * am + (1.f - sb) * ad;
      size_t orow = (size_t)b * S_ + (size_t)seg * SEG_ + t * 64 + irow;
      att[orow * 512 + h * 64 + v] = f2bf(o);
    }
  }
}

// ---------------------------------------------------------------------------
// Residual + LayerNorm, one wave per row (16 elems/lane, wave-only reduce).
// x2 bf16 ws; x raw (flag dtype); out raw (flag dtype). grid = M/4, block 256.
// ---------------------------------------------------------------------------
__global__ __launch_bounds__(256)
void ln_kernel(const unsigned short* __restrict__ x2, const void* __restrict__ xraw,
               const unsigned short* __restrict__ gamma_bf, const unsigned short* __restrict__ beta_bf,
               void* __restrict__ out, const int* __restrict__ flagp) {
  const int isf = *flagp;
  const int w = threadIdx.x >> 6, lane = threadIdx.x & 63;
  const int row = blockIdx.x * 4 + w;
  const size_t rb = (size_t)row * 1024 + lane * 16;
  u16x8 a0 = *(const u16x8*)(x2 + rb);
  u16x8 a1 = *(const u16x8*)(x2 + rb + 8);
  float xv[16];
  if (isf) {
    const float* xf = (const float*)xraw + rb;
    for (int j = 0; j < 16; j += 4) {
      f32x4 t = *(const f32x4*)(xf + j);
      xv[j] = t[0]; xv[j + 1] = t[1]; xv[j + 2] = t[2]; xv[j + 3] = t[3];
    }
  } else {
    const unsigned short* xu = (const unsigned short*)xraw + rb;
    u16x8 t0 = *(const u16x8*)xu, t1 = *(const u16x8*)(xu + 8);
    for (int j = 0; j < 8; j++) { xv[j] = bf2f(t0[j]); xv[8 + j] = bf2f(t1[j]); }
  }
  float vv[16], s = 0.f, ss = 0.f;
  for (int j = 0; j < 8; j++) {
    vv[j] = bf2f(a0[j]) + xv[j];
    vv[8 + j] = bf2f(a1[j]) + xv[8 + j];
  }
  for (int j = 0; j < 16; j++) { s += vv[j]; ss += vv[j] * vv[j]; }
  for (int off = 32; off >= 1; off >>= 1) { s += __shfl_xor(s, off); ss += __shfl_xor(ss, off); }
  float mean = s * (1.f / 1024.f);
  float var = ss * (1.f / 1024.f) - mean * mean;
  float rs = rsqrtf(var + 1e-5f);
  u16x8 g0 = *(const u16x8*)(gamma_bf + lane * 16);
  u16x8 g1 = *(const u16x8*)(gamma_bf + lane * 16 + 8);
  u16x8 be0 = *(const u16x8*)(beta_bf + lane * 16);
  u16x8 be1 = *(const u16x8*)(beta_bf + lane * 16 + 8);
  if (isf) {
    float* op = (float*)out + rb;
    for (int j = 0; j < 16; j += 4) {
      f32x4 o;
      for (int q = 0; q < 4; q++) {
        int jj = j + q;
        float gg = jj < 8 ? bf2f(g0[jj]) : bf2f(g1[jj - 8]);
        float bb = jj < 8 ? bf2f(be0[jj]) : bf2f(be1[jj - 8]);
        o[q] = (vv[jj] - mean) * rs * gg + bb;
      }
      *(f32x4*)(op + j) = o;
    }
  } else {
    u16x8 o0, o1;
    for (int j = 0; j < 8; j++) {
      o0[j] = f2bf((vv[j] - mean) * rs * bf2f(g0[j]) + bf2f(be0[j]));
      o1[j] = f2bf((vv[8 + j] - mean) * rs * bf2f(g1[j]) + bf2f(be1[j]));
    }
    *(u16x8*)((unsigned short*)out + rb) = o0;
    *(u16x8*)((unsigned short*)out + rb + 8) = o1;
  }
}

// ---------------------------------------------------------------------------
extern "C" void kernel_launch(void* const* d_in, const int* in_sizes, int n_in,
                              void* d_out, int out_size, void* d_ws, size_t ws_size,
                              hipStream_t stream) {
  const void* x     = d_in[0];
  const void* Wq    = d_in[1];
  const void* Wk    = d_in[2];
  const void* Wv    = d_in[3];
  const void* Wo    = d_in[4];
  const void* betas = d_in[5];
  const void* W1    = d_in[6];
  const void* b1    = d_in[7];
  const void* W2    = d_in[8];
  const void* b2    = d_in[9];
  const void* gamma = d_in[10];
  const void* beta  = d_in[11];

  char* ws = (char*)d_ws;
  size_t off = 0;
  auto alloc = [&](size_t bytes) { char* p = ws + off; off += (bytes + 255) & ~(size_t)255; return p; };

  const int M = B_ * S_;                       // 16384
  int* flag = (int*)alloc(256);
  unsigned short* W1T = (unsigned short*)alloc((size_t)4096 * 1024 * 2);   // 8 MiB
  unsigned short* W2T = (unsigned short*)alloc((size_t)1024 * 4096 * 2);   // 8 MiB
  unsigned short* WqkvT = (unsigned short*)alloc((size_t)QKVN * 1024 * 2); // 3 MiB
  unsigned short* WoT = (unsigned short*)alloc((size_t)1024 * 512 * 2);    // 1 MiB
  unsigned short* betas_bf = (unsigned short*)alloc(512 * 2);
  unsigned short* b1_bf    = (unsigned short*)alloc(4096 * 2);
  unsigned short* b2_bf    = (unsigned short*)alloc(1024 * 2);
  unsigned short* gamma_bf = (unsigned short*)alloc(1024 * 2);
  unsigned short* beta_bf  = (unsigned short*)alloc(1024 * 2);
  float* Mseg = (float*)alloc((size_t)B_ * H_ * NSEG_ * 4096 * 4);         // 4 MiB
  float* zseg = (float*)alloc((size_t)B_ * H_ * NSEG_ * 64 * 4);           // 64 KiB
  unsigned short* qkvb = (unsigned short*)alloc((size_t)M * QKVN * 2);     // 48 MiB
  unsigned short* x1   = qkvb;                 // 32 MiB alias (qkv dead after attn)
  unsigned short* xbf  = (unsigned short*)d_out;   // 32 MiB x-as-bf16 (dead before attn out)
  unsigned short* attb = (unsigned short*)d_out;   // 16 MiB in d_out (dead before MLP)
  unsigned short* hsml = (unsigned short*)d_out;   // 64 MiB MLP hidden fallback (dead before LN)

  if (off > ws_size) return;

  // full-M MLP hidden (128 MiB) if workspace allows; else chunked via d_out
  size_t off_save = off;
  unsigned short* hbig = (unsigned short*)alloc((size_t)M * 4096 * 2);     // 128 MiB
  const bool bigws = (off <= ws_size);
  if (!bigws) off = off_save;

  dtype_probe<<<1, 256, 0, stream>>>((const unsigned short*)gamma, flag);

  // all dtype conversions (5 small params + x) in one dispatch
  convert_all<<<dim3(30 + M * 1024 / 8 / 256), 256, 0, stream>>>(
      betas, b1, b2, gamma, beta, x,
      betas_bf, b1_bf, b2_bf, gamma_bf, beta_bf, xbf, flag);

  // all 6 weight transposes in one dispatch (10240 32x32 tiles)
  transpose_all<<<dim3(10240), dim3(32, 8), 0, stream>>>(
      Wq, Wk, Wv, Wo, W1, W2, WqkvT, WoT, W1T, W2T, flag);

  // fused QKV: (16384,1024)@(1024,1536) -> qkvb.  grid 64x6 = 384 blocks
  gemm256<0, 0><<<dim3(384), 512, 0, stream>>>(xbf, WqkvT, nullptr, qkvb, M, QKVN, 1024);

  attn_stats<<<dim3(NSEG_, H_, B_), 256, 0, stream>>>(qkvb, Mseg, zseg);
  attn_prefix<<<dim3(B_ * H_), 256, 0, stream>>>(Mseg, zseg);
  attn_core<<<dim3(8, NSEG_, H_ * B_), 256, 0, stream>>>(qkvb, betas_bf, Mseg, zseg, attb);

  // out proj: (16384,512)@(512,1024) -> x1 (qkv region dead).  grid 256
  gemm256<0, 0><<<dim3(256), 512, 0, stream>>>(attb, WoT, nullptr, x1, M, 1024, 512);

  if (bigws) {
    // full-M MLP: W1 grid 64x16=1024 (4/CU even), W2 grid 64x4=256 (1/CU even)
    gemm256<1, 1><<<dim3(1024), 512, 0, stream>>>(x1, W1T, b1_bf, hbig, M, 4096, 1024);
    gemm256<1, 0><<<dim3(256), 512, 0, stream>>>(hbig, W2T, b2_bf, x1, M, 1024, 4096);
  } else {
    // chunked fallback: hidden (64 MiB) in d_out
    for (int c = 0; c < 2; c++) {
      unsigned short* x1c = x1 + (size_t)c * 8192 * 1024;
      gemm256<1, 1><<<dim3(512), 512, 0, stream>>>(x1c, W1T, b1_bf, hsml, 8192, 4096, 1024);
      gemm256<1, 0><<<dim3(128), 512, 0, stream>>>(hsml, W2T, b2_bf, x1c, 8192, 1024, 4096);
    }
  }

  ln_kernel<<<dim3(M / 4), 256, 0, stream>>>(x1, x, gamma_bf, beta_bf, d_out, flag);
}